// Round 15
// baseline (6719.344 us; speedup 1.0000x reference)
//
#include <hip/hip_runtime.h>

#define Bz 32
#define Tz 512
#define Dz 512
#define Lz 1024
#define Mz 10
#define G4D 2048
#define FP 32
#define NBQ 4                 // blocks per batch
#define NBLK (Bz*NBQ)         // 128
// ws int-region offsets
#define OFF_FQ   0                        // fQ[32][4][FP] = 4096
#define OFF_HX   4096                     // hx[2][32][4][128] f32 = 32768
#define OFF_WQ   36864                    // Wq[4][256][512] u32 = 524288 (2MB)
#define OFF_M2   561152                   // M2[32768][1024] u32 = 128MB
#define OFF_XW   34115584                 // xw[16384][1024] u32 = 64MB
#define NEED_I   50892800
// k_pre tiles
#define PM 128
#define PN 128
#define PK 32

typedef unsigned long long u64;
typedef unsigned u32;
typedef _Float16 f16x8 __attribute__((ext_vector_type(8)));
typedef float f32x4 __attribute__((ext_vector_type(4)));
typedef _Float16 half2_t __attribute__((ext_vector_type(2)));

#if defined(__has_builtin)
#if __has_builtin(__builtin_amdgcn_fdot2)
#define HAS_FDOT2 1
#endif
#endif

__device__ __forceinline__ float fsig(float x) { return 1.0f / (1.0f + __expf(-x)); }
__device__ __forceinline__ int ld_rlx(const int* p) {
  return __hip_atomic_load(p, __ATOMIC_RELAXED, __HIP_MEMORY_SCOPE_AGENT);
}
__device__ __forceinline__ void st_rlx(int* p, int v) {
  __hip_atomic_store(p, v, __ATOMIC_RELAXED, __HIP_MEMORY_SCOPE_AGENT);
}
__device__ __forceinline__ float ld_rlxf(const float* p) {
  return __hip_atomic_load(p, __ATOMIC_RELAXED, __HIP_MEMORY_SCOPE_AGENT);
}
__device__ __forceinline__ void st_rlxf(float* p, float v) {
  __hip_atomic_store(p, v, __ATOMIC_RELAXED, __HIP_MEMORY_SCOPE_AGENT);
}
__device__ __forceinline__ u32 pack16(float a, float b) {
  unsigned short la = __builtin_bit_cast(unsigned short, (_Float16)a);
  unsigned short lb = __builtin_bit_cast(unsigned short, (_Float16)b);
  return (u32)la | ((u32)lb << 16);
}
__device__ __forceinline__ float lo16(u32 v) {
  return (float)__builtin_bit_cast(half2_t, v)[0];
}
__device__ __forceinline__ float hi16(u32 v) {
  return (float)__builtin_bit_cast(half2_t, v)[1];
}
__device__ __forceinline__ float dot2f(u32 xu, u32 wu, float acc) {
  half2_t xh = __builtin_bit_cast(half2_t, xu);
  half2_t wh = __builtin_bit_cast(half2_t, wu);
#ifdef HAS_FDOT2
  return __builtin_amdgcn_fdot2(xh, wh, acc, false);
#else
  return acc + (float)xh[0]*(float)wh[0] + (float)xh[1]*(float)wh[1];
#endif
}
#define VWAIT() asm volatile("s_waitcnt vmcnt(0)" ::: "memory")

// ---------------- K0 (once): xw_f16[bt][j] = x[bt,:].W_ih[j,0:512] + b_ih[j] + b_hh[j] ----------------
__global__ __launch_bounds__(256) void k_pre(
    const float* __restrict__ x, const float* __restrict__ W_ih,
    const float* __restrict__ b_ih, const float* __restrict__ b_hh,
    u32* __restrict__ xwu)
{
  __shared__ float As[PM][PK+1];
  __shared__ float Bs[PN][PK+1];
  const int m0 = blockIdx.x*PM, n0 = blockIdx.y*PN;
  const int tid = threadIdx.x;
  const int mg = tid >> 4, ng = tid & 15;
  float acc[8][8] = {};
  for (int k0 = 0; k0 < Dz; k0 += PK) {
    for (int i = tid; i < PM*(PK/4); i += 256) {
      int row = i >> 3, c4 = (i & 7) << 2;
      float4 v = *reinterpret_cast<const float4*>(&x[(size_t)(m0+row)*Dz + k0 + c4]);
      As[row][c4] = v.x; As[row][c4+1] = v.y; As[row][c4+2] = v.z; As[row][c4+3] = v.w;
    }
    for (int i = tid; i < PN*(PK/4); i += 256) {
      int row = i >> 3, c4 = (i & 7) << 2;
      float4 v = *reinterpret_cast<const float4*>(&W_ih[(size_t)(n0+row)*(2*Dz) + k0 + c4]);
      Bs[row][c4] = v.x; Bs[row][c4+1] = v.y; Bs[row][c4+2] = v.z; Bs[row][c4+3] = v.w;
    }
    __syncthreads();
    #pragma unroll 8
    for (int k = 0; k < PK; k++) {
      float a8[8], b8[8];
      #pragma unroll
      for (int r = 0; r < 8; r++) a8[r] = As[mg*8+r][k];
      #pragma unroll
      for (int s = 0; s < 8; s++) b8[s] = Bs[ng*8+s][k];
      #pragma unroll
      for (int r = 0; r < 8; r++)
        #pragma unroll
        for (int s = 0; s < 8; s++) acc[r][s] += a8[r]*b8[s];
    }
    __syncthreads();
  }
  const int nb = n0 + ng*8;
  #pragma unroll
  for (int r = 0; r < 8; r++) {
    int m = m0 + mg*8 + r;
    #pragma unroll
    for (int s2 = 0; s2 < 4; s2++) {
      int n = nb + 2*s2;
      xwu[(size_t)m*1024 + (n >> 1)] =
          pack16(acc[r][2*s2]   + b_ih[n]   + b_hh[n],
                 acc[r][2*s2+1] + b_ih[n+1] + b_hh[n+1]);
    }
  }
}

// ---------------- K1 (once): M2[m][j] = memory[m,:] . W_ic[j,:]  (f16 pairs, MFMA) ----------------
__global__ __launch_bounds__(512) void k_m2(
    const float* __restrict__ memory, const float* __restrict__ W_ih,
    u32* __restrict__ M2u)
{
  __shared__ __align__(16) u32 smem[149760/4];
  u32* Bs = smem;              // [128][260]
  u32* As = smem + 33280;      // [16][260]
  const int tid = threadIdx.x;
  const int n0 = blockIdx.x * 128, mc = blockIdx.y;
  for (int i = tid; i < 128*256; i += 512) {
    int jl = i >> 8, ku = i & 255;
    float2 wv = *reinterpret_cast<const float2*>(&W_ih[(size_t)(n0+jl)*(2*Dz) + 512 + 2*ku]);
    Bs[jl*260 + (ku ^ ((jl & 7) << 2))] = pack16(wv.x, wv.y);
  }
  __syncthreads();
  const int w = tid >> 6, lane = tid & 63;
  const int fr = lane & 15, kq = (lane >> 4) << 2;
  const int frsw = (fr & 7) << 2;
  for (int mt = 0; mt < 128; ++mt) {
    const int m0 = mc*2048 + mt*16;
    for (int i = tid; i < 16*256; i += 512) {
      int r = i >> 8, ku = i & 255;
      float2 mv = *reinterpret_cast<const float2*>(&memory[(size_t)(m0+r)*Dz + 2*ku]);
      As[r*260 + (ku ^ ((r & 7) << 2))] = pack16(mv.x, mv.y);
    }
    __syncthreads();
    f32x4 acc = {0.f, 0.f, 0.f, 0.f};
    #pragma unroll
    for (int ks = 0; ks < 16; ++ks) {
      int col = (kq + ks*16) ^ frsw;
      f16x8 av = *reinterpret_cast<const f16x8*>(As + fr*260 + col);
      f16x8 bv = *reinterpret_cast<const f16x8*>(Bs + (w*16 + fr)*260 + col);
      acc = __builtin_amdgcn_mfma_f32_16x16x32_f16(av, bv, acc, 0, 0, 0);
    }
    #pragma unroll
    for (int i = 0; i < 4; ++i) {
      float oth = __shfl_xor(acc[i], 1);
      if (!(lane & 1)) {
        int m = m0 + ((lane >> 4) << 2) + i;
        int j = n0 + w*16 + fr;
        M2u[(size_t)m*1024 + (j >> 1)] = pack16(acc[i], oth);
      }
    }
    __syncthreads();
  }
}

// ---------------- K2 (once): Wq[q][kp][pos] = pack(Whh[j][2kp], Whh[j][2kp+1]) ----------------
// pos = g*128 + jj ; j = 512*g + 128*q + jj   (slice q = gate rows for d in [128q,128q+128))
__global__ __launch_bounds__(512) void k_packh(
    const float* __restrict__ W_hh, u32* __restrict__ Wq)
{
  const int kp = blockIdx.x;
  for (int idx = threadIdx.x; idx < 2048; idx += 512) {
    int q = idx >> 9, pos = idx & 511;
    int g = pos >> 7, jj = pos & 127;
    int j = 512*g + 128*q + jj;
    float2 wv = *reinterpret_cast<const float2*>(&W_hh[(size_t)j*Dz + 2*kp]);
    Wq[(((size_t)q*256 + kp) << 9) + pos] = pack16(wv.x, wv.y);
  }
}

// ---------------- Persistent kernel: 4 self-contained blocks per batch ----------------
// block = b*4 + q. Block q: streams Wq[q] (512KB, L2-resident) with fdot2,
// computes full gates+LSTM for d in [128q,128q+128), exchanges h-quarters with
// its 3 siblings (per-batch flags; no global barrier), tail all-local.
__global__ __launch_bounds__(512) void k_persist(
    const float* __restrict__ memory, const int* __restrict__ lens,
    const float* __restrict__ W_g,  const float* __restrict__ b_g,
    const u32* __restrict__ xwu, const u32* __restrict__ M2u,
    const u32* __restrict__ Wq,
    float* __restrict__ hx, int* __restrict__ fQ,
    float* __restrict__ ctx_out, float* __restrict__ align_out,
    float* __restrict__ term_out)
{
  const int blk = blockIdx.x, tid = threadIdx.x;
  const int b = blk >> 2, q = blk & 3;

  __shared__ float pgemv[4][512];     // GEMV k-group partials | final-ctx partials
  __shared__ float gctxl[512];        // ctx gate contribution (pos-indexed)
  __shared__ float wsm[Lz];
  __shared__ float hf[Dz];            // full h(t) f32
  __shared__ float cs[128];           // own cell-state quarter
  __shared__ u32   xp[256];           // h(t-1) packed f16 pairs
  __shared__ float2 pg2[2][256];      // gctx einsum partials
  __shared__ float phis[3*Mz], prm[3*Mz], lom[Mz], him[Mz];
  __shared__ int rng[2];

  if (tid < 128) cs[tid] = 0.f;
  if (tid < 256) xp[tid] = 0u;                       // h(-1) = 0
  for (int i = tid; i < 512; i += 512) gctxl[i] = 0.f; // ctx(-1) = 0
  __syncthreads();

  const uint4* wq4 = reinterpret_cast<const uint4*>(Wq) + (size_t)q*32768;
  const int kg = tid >> 7, tq = tid & 127;

  for (int t = 0; t < Tz; ++t) {
    // ---- GEMV: gates_h partials (streams 512KB from L2; xp = h(t-1) f16)
    {
      const uint4* wr = wq4 + tq;
      float a0 = 0.f, a1 = 0.f, a2 = 0.f, a3 = 0.f;
      const int k0 = kg << 6;
      #pragma unroll 4
      for (int kp = k0; kp < k0 + 64; ++kp) {
        uint4 wv = wr[(size_t)kp << 7];
        u32 xv = xp[kp];
        a0 = dot2f(xv, wv.x, a0);
        a1 = dot2f(xv, wv.y, a1);
        a2 = dot2f(xv, wv.z, a2);
        a3 = dot2f(xv, wv.w, a3);
      }
      *reinterpret_cast<float4*>(&pgemv[kg][tq << 2]) = make_float4(a0, a1, a2, a3);
    }
    __syncthreads();

    // ---- gates + LSTM for d in [128q, 128q+128)   (gate order i,f,g,o)
    if (tid < 128) {
      const int dl = tid;
      const size_t xwb = ((size_t)(b*Tz + t)) << 10;
      float gv[4];
      #pragma unroll
      for (int g = 0; g < 4; ++g) {
        int pos = (g << 7) + dl;
        float s = pgemv[0][pos] + pgemv[1][pos] + pgemv[2][pos] + pgemv[3][pos]
                + gctxl[pos];
        int j = (g << 9) + (q << 7) + dl;
        u32 xv = xwu[xwb + (j >> 1)];
        s += (j & 1) ? hi16(xv) : lo16(xv);
        gv[g] = s;
      }
      float ig = fsig(gv[0]);
      float fg = fsig(gv[1]);
      float gg = tanhf(gv[2]);
      float og = fsig(gv[3]);
      float cn = fg*cs[dl] + ig*gg;
      float hn = og*tanhf(cn);
      cs[dl] = cn;
      hf[(q << 7) + dl] = hn;
      st_rlxf(&hx[(((t & 1)*Bz + b)*NBQ + q)*128 + dl], hn);   // publish own quarter
    }
    VWAIT();
    __syncthreads();
    if (tid == 0) st_rlx(&fQ[(b*NBQ + q)*FP], t+1);

    // ---- wait siblings, gather their h-quarters
    if (tid < NBQ) {
      while (ld_rlx(&fQ[(b*NBQ + tid)*FP]) < t+1) __builtin_amdgcn_s_sleep(1);
    }
    __syncthreads();
    if (tid < 384) {
      int rp = tid >> 7;
      int p = rp + (rp >= q ? 1 : 0);
      int dl2 = tid & 127;
      hf[(p << 7) + dl2] = ld_rlxf(&hx[(((t & 1)*Bz + b)*NBQ + p)*128 + dl2]);
    }
    __syncthreads();
    if (tid < 256) xp[tid] = pack16(hf[2*tid], hf[2*tid+1]);   // for next GEMV

    // ---- phi[m] = hf . W_g[m,:] + b_g[m]  (16 lanes/m)
    if (tid < 16*3*Mz) {
      int m = tid >> 4, l16 = tid & 15;
      const float4* wr = reinterpret_cast<const float4*>(W_g + m*Dz);
      const float4* hr = reinterpret_cast<const float4*>(hf);
      float s = 0.f;
      #pragma unroll
      for (int i = 0; i < 8; i++) {
        float4 wv = wr[l16 + (i<<4)];
        float4 hv = hr[l16 + (i<<4)];
        s += wv.x*hv.x + wv.y*hv.y + wv.z*hv.z + wv.w*hv.w;
      }
      s += __shfl_xor(s, 1);
      s += __shfl_xor(s, 2);
      s += __shfl_xor(s, 4);
      s += __shfl_xor(s, 8);
      if (l16 == 0) phis[m] = s + b_g[m];
    }
    __syncthreads();

    // ---- GMM params + active range
    if (tid < Mz) {
      float ks = expf(phis[tid]);
      float be = expf(phis[Mz + tid]);
      prm[tid]      = ks;
      prm[Mz + tid] = expf(-phis[Mz + tid]);   // 1/beta
      lom[tid] = ks - 0.5f - 25.f*be;          // sig(-25) < fp32 visibility
      him[tid] = ks + 0.5f + 25.f*be;
    }
    __syncthreads();
    if (tid == 0) {
      float mx = -1e30f;
      #pragma unroll
      for (int m = 0; m < Mz; m++) mx = fmaxf(mx, phis[2*Mz + m]);
      float ae[Mz], ssum = 0.f;
      #pragma unroll
      for (int m = 0; m < Mz; m++) { ae[m] = expf(phis[2*Mz + m] - mx); ssum += ae[m]; }
      float lo = 1e30f, hi = -1e30f;
      #pragma unroll
      for (int m = 0; m < Mz; m++) {
        prm[2*Mz + m] = ae[m] / ssum;
        lo = fminf(lo, lom[m]); hi = fmaxf(hi, him[m]);
      }
      int llo = lo > 0.f ? (int)floorf(lo) : 0;
      if (llo > Lz) llo = Lz;
      int lhi = hi < (float)Lz ? (int)ceilf(hi) + 1 : Lz;
      if (lhi > Lz) lhi = Lz;
      rng[0] = llo; rng[1] = lhi;
    }
    __syncthreads();
    const int llo = rng[0], lhi = rng[1];

    // ---- w on active range
    for (int l = llo + tid; l < lhi; l += 512) {
      float u = (float)l;
      float t1 = 0.f, t0 = 0.f;
      #pragma unroll
      for (int m = 0; m < Mz; m++) {
        float ks = prm[m], ib = prm[Mz + m], al = prm[2*Mz + m];
        t1 += al * fsig((u + 0.5f - ks) * ib);
        t0 += al * fsig((u - 0.5f - ks) * ib);
      }
      wsm[l] = t1 - t0;
    }
    __syncthreads();

    if (t < Tz-1) {
      // ---- gctx(t+1) for own 512-j slice: cols 256g + 64q + jj2
      {
        const int seg = tid >> 8, tc = tid & 255;
        const int g = tc >> 6, jj2 = tc & 63;
        const int col = (g << 8) + (q << 6) + jj2;
        const u32* m2c = M2u + (((size_t)b << 10) << 10) + col;
        float alo = 0.f, ahi = 0.f;
        for (int l = llo + seg; l < lhi; l += 2) {
          float wl = wsm[l];
          u32 v = m2c[(size_t)l << 10];
          alo = fmaf(wl, lo16(v), alo);
          ahi = fmaf(wl, hi16(v), ahi);
        }
        pg2[seg][tc] = make_float2(alo, ahi);
      }
      __syncthreads();
      if (tid < 256) {
        float2 v0 = pg2[0][tid], v1 = pg2[1][tid];
        int g = tid >> 6, jj2 = tid & 63;
        gctxl[(g << 7) + 2*jj2]     = v0.x + v1.x;
        gctxl[(g << 7) + 2*jj2 + 1] = v0.y + v1.y;
      }
      __syncthreads();
    } else if (q == 0) {
      // ---- final step: ctx_out = sum_l w_l * memory[b,l,:]
      {
        const int grp = tid >> 7, d0 = (tid & 127) << 2;
        const float* mb = memory + (size_t)b*Lz*Dz + d0;
        float4 a = make_float4(0.f, 0.f, 0.f, 0.f);
        for (int l = llo + grp; l < lhi; l += 4) {
          float wl = wsm[l];
          float4 m0 = *reinterpret_cast<const float4*>(&mb[(size_t)l*Dz]);
          a.x = fmaf(wl, m0.x, a.x); a.y = fmaf(wl, m0.y, a.y);
          a.z = fmaf(wl, m0.z, a.z); a.w = fmaf(wl, m0.w, a.w);
        }
        *reinterpret_cast<float4*>(&pgemv[grp][d0]) = a;
      }
      __syncthreads();
      ctx_out[b*Dz + tid] = pgemv[0][tid] + pgemv[1][tid] + pgemv[2][tid] + pgemv[3][tid];
      if (tid == 0) {
        float u = (float)(lens[b] - 1);
        float t1 = 0.f;
        #pragma unroll
        for (int m = 0; m < Mz; m++)
          t1 += prm[2*Mz + m] * fsig((u + 0.5f - prm[m]) * prm[Mz + m]);
        term_out[b] = 1.0f - t1;
      }
    }

    // ---- alignment row (q==0 only; off critical path)
    if (q == 0) {
      for (int l = llo + tid; l < lhi; l += 512)
        align_out[((size_t)b*Tz + t)*Lz + l] = wsm[l];
    }
  }
}

// ================= fallback (small ws): two-kernel loop path =================
__global__ __launch_bounds__(256) void k_gemm(
    const float* __restrict__ x_all, const float* __restrict__ ctxs,
    const float* __restrict__ h, const float* __restrict__ W_ih,
    const float* __restrict__ W_hh, float* __restrict__ partial, int t)
{
  __shared__ float Xs[Bz][130];
  __shared__ float Wt[128][130];
  const int jt = blockIdx.x, kcb = blockIdx.y;
  const int j0 = jt*128, k0 = kcb*128;
  const int tid = threadIdx.x;
  for (int i = tid; i < Bz*128; i += 256) {
    int bb = i >> 7, kk = i & 127;
    int k = k0 + kk;
    float v;
    if (k < Dz)        v = x_all[((size_t)bb*Tz + t)*Dz + k];
    else if (k < 2*Dz) v = ctxs[bb*Dz + (k - Dz)];
    else               v = h[bb*Dz + (k - 2*Dz)];
    Xs[bb][kk] = v;
  }
  {
    const float* Wsrc; int ldw, col0;
    if (k0 < 2*Dz) { Wsrc = W_ih; ldw = 2*Dz; col0 = k0; }
    else           { Wsrc = W_hh; ldw = Dz;   col0 = k0 - 2*Dz; }
    for (int i = tid; i < 128*32; i += 256) {
      int jj = i >> 5, k4 = (i & 31) << 2;
      float4 v = *reinterpret_cast<const float4*>(&Wsrc[(size_t)(j0 + jj)*ldw + col0 + k4]);
      Wt[jj][k4] = v.x; Wt[jj][k4+1] = v.y; Wt[jj][k4+2] = v.z; Wt[jj][k4+3] = v.w;
    }
  }
  __syncthreads();
  const int jg = tid & 31, bg = tid >> 5;
  const int bl = bg << 2;
  float acc[4][4] = {};
  #pragma unroll 4
  for (int k = 0; k < 128; k += 2) {
    float2 xv[4], wv[4];
    #pragma unroll
    for (int b2 = 0; b2 < 4; b2++)
      xv[b2] = *reinterpret_cast<const float2*>(&Xs[bl + b2][k]);
    #pragma unroll
    for (int jj = 0; jj < 4; jj++)
      wv[jj] = *reinterpret_cast<const float2*>(&Wt[jg + (jj << 5)][k]);
    #pragma unroll
    for (int jj = 0; jj < 4; jj++)
      #pragma unroll
      for (int b2 = 0; b2 < 4; b2++)
        acc[jj][b2] += wv[jj].x * xv[b2].x + wv[jj].y * xv[b2].y;
  }
  #pragma unroll
  for (int jj = 0; jj < 4; jj++)
    #pragma unroll
    for (int b2 = 0; b2 < 4; b2++)
      partial[((size_t)kcb*Bz + (bl + b2))*G4D + j0 + jg + (jj << 5)] = acc[jj][b2];
}

__global__ __launch_bounds__(512) void k_fused(
    const float* __restrict__ partial, const float* __restrict__ b_ih,
    const float* __restrict__ b_hh,
    float* __restrict__ h, float* __restrict__ c,
    const float* __restrict__ W_g, const float* __restrict__ b_g,
    const float* __restrict__ memory, const int* __restrict__ lens,
    float* __restrict__ ctxs, float* __restrict__ ctx_out,
    float* __restrict__ align_out, float* __restrict__ term_out,
    int t, int final_, int nkc)
{
  const int b = blockIdx.x, tid = threadIdx.x;
  __shared__ float4 gs4[G4D/4];
  __shared__ float hsb[Dz];
  __shared__ float phis[3*Mz];
  __shared__ float prm[3*Mz];
  __shared__ float wsm[Lz];
  __shared__ int   rng[2];
  float* gs = (float*)gs4;
  {
    int j = 4*tid;
    float4 bi = *reinterpret_cast<const float4*>(&b_ih[j]);
    float4 bh = *reinterpret_cast<const float4*>(&b_hh[j]);
    float4 s = make_float4(bi.x+bh.x, bi.y+bh.y, bi.z+bh.z, bi.w+bh.w);
    const float4* pp = reinterpret_cast<const float4*>(partial) + (size_t)b*(G4D/4) + tid;
    for (int kcb = 0; kcb < nkc; kcb++) {
      float4 p = pp[(size_t)kcb*Bz*(G4D/4)];
      s.x += p.x; s.y += p.y; s.z += p.z; s.w += p.w;
    }
    gs4[tid] = s;
  }
  __syncthreads();
  {
    const int d = tid;
    float ig = 1.0f / (1.0f + expf(-gs[d]));
    float fg = 1.0f / (1.0f + expf(-gs[Dz + d]));
    float gg = tanhf(gs[2*Dz + d]);
    float og = 1.0f / (1.0f + expf(-gs[3*Dz + d]));
    float cn = fg * c[b*Dz + d] + ig * gg;
    float hn = og * tanhf(cn);
    c[b*Dz + d] = cn;
    h[b*Dz + d] = hn;
    hsb[d] = hn;
  }
  __syncthreads();
  if (tid < 16*3*Mz) {
    int m = tid >> 4, l16 = tid & 15;
    float s = 0.f;
    #pragma unroll 4
    for (int k = l16; k < Dz; k += 16) s += W_g[m*Dz + k] * hsb[k];
    s += __shfl_xor(s, 1);
    s += __shfl_xor(s, 2);
    s += __shfl_xor(s, 4);
    s += __shfl_xor(s, 8);
    if (l16 == 0) phis[m] = s + b_g[m];
  }
  __syncthreads();
  if (tid == 0) {
    float mx = -1e30f;
    #pragma unroll
    for (int m = 0; m < Mz; m++) mx = fmaxf(mx, phis[2*Mz + m]);
    float ae[Mz], ssum = 0.f;
    #pragma unroll
    for (int m = 0; m < Mz; m++) { ae[m] = expf(phis[2*Mz + m] - mx); ssum += ae[m]; }
    float lo = 1e30f, hi = -1e30f;
    #pragma unroll
    for (int m = 0; m < Mz; m++) {
      float ks = expf(phis[m]);
      float be = expf(phis[Mz + m]);
      prm[m]        = ks;
      prm[Mz + m]   = expf(-phis[Mz + m]);
      prm[2*Mz + m] = ae[m] / ssum;
      lo = fminf(lo, ks - 0.5f - 25.f*be);
      hi = fmaxf(hi, ks + 0.5f + 25.f*be);
    }
    int llo = lo > 0.f ? (int)floorf(lo) : 0;
    if (llo > Lz) llo = Lz;
    int lhi = hi < (float)Lz ? (int)ceilf(hi) + 1 : Lz;
    if (lhi > Lz) lhi = Lz;
    rng[0] = llo; rng[1] = lhi;
  }
  __syncthreads();
  const int llo = rng[0], lhi = rng[1];
  for (int l = llo + tid; l < lhi; l += 512) {
    float u = (float)l;
    float t1 = 0.f, t0 = 0.f;
    #pragma unroll
    for (int m = 0; m < Mz; m++) {
      float ks = prm[m], ib = prm[Mz + m], al = prm[2*Mz + m];
      t1 += al * fsig((u + 0.5f - ks) * ib);
      t0 += al * fsig((u - 0.5f - ks) * ib);
    }
    float w = t1 - t0;
    wsm[l] = w;
    align_out[((size_t)b*Tz + t)*Lz + l] = w;
  }
  __syncthreads();
  {
    const float* mb = memory + (size_t)b*Lz*Dz + tid;
    float acc = 0.f;
    #pragma unroll 4
    for (int l = llo; l < lhi; l++)
      acc += wsm[l] * mb[(size_t)l*Dz];
    ctxs[b*Dz + tid] = acc;
    if (final_) ctx_out[b*Dz + tid] = acc;
  }
  if (final_ && tid == 0) {
    float u = (float)(lens[b] - 1);
    float t1 = 0.f;
    #pragma unroll
    for (int m = 0; m < Mz; m++)
      t1 += prm[2*Mz + m] * fsig((u + 0.5f - prm[m]) * prm[Mz + m]);
    term_out[b] = 1.0f - t1;
  }
}

extern "C" void kernel_launch(void* const* d_in, const int* in_sizes, int n_in,
                              void* d_out, int out_size, void* d_ws, size_t ws_size,
                              hipStream_t stream)
{
  (void)in_sizes; (void)n_in; (void)out_size;
  const float* x    = (const float*)d_in[0];
  const float* mem  = (const float*)d_in[1];
  const int*   lens = (const int*)d_in[2];
  const float* W_ih = (const float*)d_in[3];
  const float* W_hh = (const float*)d_in[4];
  const float* b_ih = (const float*)d_in[5];
  const float* b_hh = (const float*)d_in[6];
  const float* W_g  = (const float*)d_in[7];
  const float* b_g  = (const float*)d_in[8];

  float* out = (float*)d_out;
  float* ctx_out   = out;                                  // [B,1,D]
  float* align_out = out + Bz*Dz;                          // [B,T,L]
  float* term_out  = out + Bz*Dz + (size_t)Bz*Tz*Lz;       // [B,1]

  const size_t needP = (size_t)NEED_I * sizeof(int);

  hipMemsetAsync(align_out, 0, (size_t)Bz*Tz*Lz*sizeof(float), stream);

  if (ws_size >= needP) {
    int*   ip  = (int*)d_ws;
    int*   fQ  = ip + OFF_FQ;
    float* hx  = (float*)(ip + OFF_HX);
    u32*   Wq  = (u32*)(ip + OFF_WQ);
    u32*   M2u = (u32*)(ip + OFF_M2);
    u32*   xwu = (u32*)(ip + OFF_XW);

    hipMemsetAsync(d_ws, 0, (size_t)OFF_HX * sizeof(int), stream);  // flags only
    k_pre<<<dim3((Bz*Tz)/PM, G4D/PN), 256, 0, stream>>>(x, W_ih, b_ih, b_hh, xwu);
    k_m2<<<dim3(16, 16), 512, 0, stream>>>(mem, W_ih, M2u);
    k_packh<<<256, 512, 0, stream>>>(W_hh, Wq);
    k_persist<<<NBLK, 512, 0, stream>>>(mem, lens, W_g, b_g, xwu, M2u, Wq,
                                        hx, fQ, ctx_out, align_out, term_out);
  } else {
    float* wsf     = (float*)d_ws;
    float* h       = wsf;
    float* c       = h + Bz*Dz;
    float* ctxs    = c + Bz*Dz;
    float* partial = ctxs + Bz*Dz;               // [12][B][4D]
    hipMemsetAsync(d_ws, 0, (size_t)(3*Bz*Dz)*sizeof(float), stream);
    for (int t = 0; t < Tz; t++) {
      k_gemm<<<dim3(G4D/128, 12), 256, 0, stream>>>(x, ctxs, h, W_ih, W_hh, partial, t);
      k_fused<<<Bz, 512, 0, stream>>>(partial, b_ih, b_hh, h, c, W_g, b_g,
                                      mem, lens, ctxs, ctx_out, align_out, term_out,
                                      t, t == Tz-1, 12);
    }
  }
}

// Round 16
// 6027.065 us; speedup vs baseline: 1.1149x; 1.1149x over previous
//
#include <hip/hip_runtime.h>

#define Bz 32
#define Tz 512
#define Dz 512
#define Lz 1024
#define Mz 10
#define G4D 2048
#define FP 32
#define NBQ 4                 // blocks per batch
#define NBLK (Bz*NBQ)         // 128
// ws int-region offsets (identical to round 15)
#define OFF_FQ   0                        // fQ[32][4][FP] = 4096
#define OFF_HX   4096                     // hx[2][32][4][128] f32 = 32768
#define OFF_WQ   36864                    // Wq[4][256][512] u32 = 524288 (2MB)
#define OFF_M2   561152                   // M2[32768][1024] u32 = 128MB
#define OFF_XW   34115584                 // xw[16384][1024] u32 = 64MB
#define NEED_I   50892800
// k_pre tiles
#define PM 128
#define PN 128
#define PK 32

typedef unsigned long long u64;
typedef unsigned u32;
typedef _Float16 f16x8 __attribute__((ext_vector_type(8)));
typedef float f32x4 __attribute__((ext_vector_type(4)));
typedef _Float16 half2_t __attribute__((ext_vector_type(2)));

#if defined(__has_builtin)
#if __has_builtin(__builtin_amdgcn_fdot2)
#define HAS_FDOT2 1
#endif
#endif

__device__ __forceinline__ float fsig(float x) { return 1.0f / (1.0f + __expf(-x)); }
__device__ __forceinline__ int ld_rlx(const int* p) {
  return __hip_atomic_load(p, __ATOMIC_RELAXED, __HIP_MEMORY_SCOPE_AGENT);
}
__device__ __forceinline__ void st_rlx(int* p, int v) {
  __hip_atomic_store(p, v, __ATOMIC_RELAXED, __HIP_MEMORY_SCOPE_AGENT);
}
__device__ __forceinline__ float ld_rlxf(const float* p) {
  return __hip_atomic_load(p, __ATOMIC_RELAXED, __HIP_MEMORY_SCOPE_AGENT);
}
__device__ __forceinline__ void st_rlxf(float* p, float v) {
  __hip_atomic_store(p, v, __ATOMIC_RELAXED, __HIP_MEMORY_SCOPE_AGENT);
}
__device__ __forceinline__ u32 pack16(float a, float b) {
  unsigned short la = __builtin_bit_cast(unsigned short, (_Float16)a);
  unsigned short lb = __builtin_bit_cast(unsigned short, (_Float16)b);
  return (u32)la | ((u32)lb << 16);
}
__device__ __forceinline__ float lo16(u32 v) {
  return (float)__builtin_bit_cast(half2_t, v)[0];
}
__device__ __forceinline__ float hi16(u32 v) {
  return (float)__builtin_bit_cast(half2_t, v)[1];
}
__device__ __forceinline__ float dot2f(u32 xu, u32 wu, float acc) {
  half2_t xh = __builtin_bit_cast(half2_t, xu);
  half2_t wh = __builtin_bit_cast(half2_t, wu);
#ifdef HAS_FDOT2
  return __builtin_amdgcn_fdot2(xh, wh, acc, false);
#else
  return acc + (float)xh[0]*(float)wh[0] + (float)xh[1]*(float)wh[1];
#endif
}
#define VWAIT() asm volatile("s_waitcnt vmcnt(0)" ::: "memory")

// ---------------- K0 (once): xw_f16[bt][j] = x[bt,:].W_ih[j,0:512] + b_ih[j] + b_hh[j] ----------------
__global__ __launch_bounds__(256) void k_pre(
    const float* __restrict__ x, const float* __restrict__ W_ih,
    const float* __restrict__ b_ih, const float* __restrict__ b_hh,
    u32* __restrict__ xwu)
{
  __shared__ float As[PM][PK+1];
  __shared__ float Bs[PN][PK+1];
  const int m0 = blockIdx.x*PM, n0 = blockIdx.y*PN;
  const int tid = threadIdx.x;
  const int mg = tid >> 4, ng = tid & 15;
  float acc[8][8] = {};
  for (int k0 = 0; k0 < Dz; k0 += PK) {
    for (int i = tid; i < PM*(PK/4); i += 256) {
      int row = i >> 3, c4 = (i & 7) << 2;
      float4 v = *reinterpret_cast<const float4*>(&x[(size_t)(m0+row)*Dz + k0 + c4]);
      As[row][c4] = v.x; As[row][c4+1] = v.y; As[row][c4+2] = v.z; As[row][c4+3] = v.w;
    }
    for (int i = tid; i < PN*(PK/4); i += 256) {
      int row = i >> 3, c4 = (i & 7) << 2;
      float4 v = *reinterpret_cast<const float4*>(&W_ih[(size_t)(n0+row)*(2*Dz) + k0 + c4]);
      Bs[row][c4] = v.x; Bs[row][c4+1] = v.y; Bs[row][c4+2] = v.z; Bs[row][c4+3] = v.w;
    }
    __syncthreads();
    #pragma unroll 8
    for (int k = 0; k < PK; k++) {
      float a8[8], b8[8];
      #pragma unroll
      for (int r = 0; r < 8; r++) a8[r] = As[mg*8+r][k];
      #pragma unroll
      for (int s = 0; s < 8; s++) b8[s] = Bs[ng*8+s][k];
      #pragma unroll
      for (int r = 0; r < 8; r++)
        #pragma unroll
        for (int s = 0; s < 8; s++) acc[r][s] += a8[r]*b8[s];
    }
    __syncthreads();
  }
  const int nb = n0 + ng*8;
  #pragma unroll
  for (int r = 0; r < 8; r++) {
    int m = m0 + mg*8 + r;
    #pragma unroll
    for (int s2 = 0; s2 < 4; s2++) {
      int n = nb + 2*s2;
      xwu[(size_t)m*1024 + (n >> 1)] =
          pack16(acc[r][2*s2]   + b_ih[n]   + b_hh[n],
                 acc[r][2*s2+1] + b_ih[n+1] + b_hh[n+1]);
    }
  }
}

// ---------------- K1 (once): M2[m][j] = memory[m,:] . W_ic[j,:]  (f16 pairs, MFMA) ----------------
__global__ __launch_bounds__(512) void k_m2(
    const float* __restrict__ memory, const float* __restrict__ W_ih,
    u32* __restrict__ M2u)
{
  __shared__ __align__(16) u32 smem[149760/4];
  u32* Bs = smem;              // [128][260]
  u32* As = smem + 33280;      // [16][260]
  const int tid = threadIdx.x;
  const int n0 = blockIdx.x * 128, mc = blockIdx.y;
  for (int i = tid; i < 128*256; i += 512) {
    int jl = i >> 8, ku = i & 255;
    float2 wv = *reinterpret_cast<const float2*>(&W_ih[(size_t)(n0+jl)*(2*Dz) + 512 + 2*ku]);
    Bs[jl*260 + (ku ^ ((jl & 7) << 2))] = pack16(wv.x, wv.y);
  }
  __syncthreads();
  const int w = tid >> 6, lane = tid & 63;
  const int fr = lane & 15, kq = (lane >> 4) << 2;
  const int frsw = (fr & 7) << 2;
  for (int mt = 0; mt < 128; ++mt) {
    const int m0 = mc*2048 + mt*16;
    for (int i = tid; i < 16*256; i += 512) {
      int r = i >> 8, ku = i & 255;
      float2 mv = *reinterpret_cast<const float2*>(&memory[(size_t)(m0+r)*Dz + 2*ku]);
      As[r*260 + (ku ^ ((r & 7) << 2))] = pack16(mv.x, mv.y);
    }
    __syncthreads();
    f32x4 acc = {0.f, 0.f, 0.f, 0.f};
    #pragma unroll
    for (int ks = 0; ks < 16; ++ks) {
      int col = (kq + ks*16) ^ frsw;
      f16x8 av = *reinterpret_cast<const f16x8*>(As + fr*260 + col);
      f16x8 bv = *reinterpret_cast<const f16x8*>(Bs + (w*16 + fr)*260 + col);
      acc = __builtin_amdgcn_mfma_f32_16x16x32_f16(av, bv, acc, 0, 0, 0);
    }
    #pragma unroll
    for (int i = 0; i < 4; ++i) {
      float oth = __shfl_xor(acc[i], 1);
      if (!(lane & 1)) {
        int m = m0 + ((lane >> 4) << 2) + i;
        int j = n0 + w*16 + fr;
        M2u[(size_t)m*1024 + (j >> 1)] = pack16(acc[i], oth);
      }
    }
    __syncthreads();
  }
}

// ---------------- K2 (once): Wq[q][kp][pos] = pack(Whh[j][2kp], Whh[j][2kp+1]) ----------------
__global__ __launch_bounds__(512) void k_packh(
    const float* __restrict__ W_hh, u32* __restrict__ Wq)
{
  const int kp = blockIdx.x;
  for (int idx = threadIdx.x; idx < 2048; idx += 512) {
    int q = idx >> 9, pos = idx & 511;
    int g = pos >> 7, jj = pos & 127;
    int j = 512*g + 128*q + jj;
    float2 wv = *reinterpret_cast<const float2*>(&W_hh[(size_t)j*Dz + 2*kp]);
    Wq[(((size_t)q*256 + kp) << 9) + pos] = pack16(wv.x, wv.y);
  }
}

// ---- intra-tail-half sync: monotonic LDS counters, 4 tail-wave leaders each ----
#define HSYNC(id, tgt) do {                                                    \
  __threadfence_block();                                                       \
  if ((tid & 63) == 0) atomicAdd(&scnt[id], 1);                                \
  while (__hip_atomic_load(&scnt[id], __ATOMIC_RELAXED,                        \
                           __HIP_MEMORY_SCOPE_WORKGROUP) < (tgt))              \
    __builtin_amdgcn_s_sleep(1);                                               \
  __threadfence_block();                                                       \
} while (0)

// ---------------- Persistent kernel: wave-specialized GEMV || TAIL ----------------
// block = b*4 + q. Waves 0-3: Whh-slice GEMV(t) from xp=h(t-1) (L2 stream).
// Waves 4-7: TAIL(t-1) = phi(h(t-1)) -> params -> w(t-1) -> gctx(t) -> align(t-1).
// Join -> LSTM(t) -> publish quarter -> poll siblings -> gather -> pack.
__global__ __launch_bounds__(512) void k_persist(
    const float* __restrict__ memory, const int* __restrict__ lens,
    const float* __restrict__ W_g,  const float* __restrict__ b_g,
    const u32* __restrict__ xwu, const u32* __restrict__ M2u,
    const u32* __restrict__ Wq,
    float* __restrict__ hx, int* __restrict__ fQ,
    float* __restrict__ ctx_out, float* __restrict__ align_out,
    float* __restrict__ term_out)
{
  const int blk = blockIdx.x, tid = threadIdx.x;
  const int b = blk >> 2, q = blk & 3;

  __shared__ float pgemv[4][512];     // rows 0-1: GEMV partials; post-loop: einsum partials
  __shared__ float gctxl[512];
  __shared__ float wsm[Lz];
  __shared__ float hf[Dz];
  __shared__ float cs[128];
  __shared__ u32   xp[256];
  __shared__ float phis[3*Mz], prm[3*Mz];
  __shared__ int   rng[2];
  __shared__ int   scnt[3];

  if (tid < 128) cs[tid] = 0.f;
  if (tid < 256) xp[tid] = 0u;       // h(-1) = 0
  if (tid < 3)   scnt[tid] = 0;
  gctxl[tid] = 0.f;                  // ctx(-1) = 0
  __syncthreads();

  const uint4* wq4 = reinterpret_cast<const uint4*>(Wq) + (size_t)q*32768;

  for (int t = 0; t < Tz; ++t) {
    // prefetch xw gate biases for LSTM(t) (hidden under GEMV)
    u32 xwp0 = 0, xwp1 = 0, xwp2 = 0, xwp3 = 0;
    if (tid < 128) {
      const size_t xwb = ((size_t)(b*Tz + t)) << 10;
      const int o = (q << 6) + (tid >> 1);
      xwp0 = xwu[xwb + o];
      xwp1 = xwu[xwb + 256 + o];
      xwp2 = xwu[xwb + 512 + o];
      xwp3 = xwu[xwb + 768 + o];
    }

    if (tid < 256) {
      // ======== GEMV half (waves 0-3): gates_h partials from xp = h(t-1)
      const int kg2 = tid >> 7, tq2 = tid & 127;
      const uint4* wr = wq4 + tq2;
      float a0 = 0.f, a1 = 0.f, a2 = 0.f, a3 = 0.f;
      const int k0 = kg2 << 7;
      #pragma unroll 4
      for (int kp = k0; kp < k0 + 128; ++kp) {
        uint4 wv = wr[(size_t)kp << 7];
        u32 xv = xp[kp];
        a0 = dot2f(xv, wv.x, a0);
        a1 = dot2f(xv, wv.y, a1);
        a2 = dot2f(xv, wv.z, a2);
        a3 = dot2f(xv, wv.w, a3);
      }
      *reinterpret_cast<float4*>(&pgemv[kg2][tq2 << 2]) = make_float4(a0, a1, a2, a3);
    } else if (t > 0) {
      // ======== TAIL half (waves 4-7): everything derived from h(t-1)
      const int t2 = tid - 256;
      const int tgt = 4 * t;
      // phi[m] = hf . W_g[m,:] + b_g[m]  (8 lanes/m, 240 threads)
      if (t2 < 8*3*Mz) {
        int m = t2 >> 3, l8 = t2 & 7;
        const float4* wr2 = reinterpret_cast<const float4*>(W_g + m*Dz);
        const float4* hr = reinterpret_cast<const float4*>(hf);
        float s = 0.f;
        #pragma unroll
        for (int i = 0; i < 16; i++) {
          float4 wv = wr2[l8 + (i << 3)];
          float4 hv = hr[l8 + (i << 3)];
          s += wv.x*hv.x + wv.y*hv.y + wv.z*hv.z + wv.w*hv.w;
        }
        s += __shfl_xor(s, 1);
        s += __shfl_xor(s, 2);
        s += __shfl_xor(s, 4);
        if (l8 == 0) phis[m] = s + b_g[m];
      }
      HSYNC(0, tgt);
      if (t2 == 0) {
        float mx = -1e30f;
        #pragma unroll
        for (int m = 0; m < Mz; m++) mx = fmaxf(mx, phis[2*Mz + m]);
        float ae[Mz], ssum = 0.f;
        #pragma unroll
        for (int m = 0; m < Mz; m++) { ae[m] = expf(phis[2*Mz + m] - mx); ssum += ae[m]; }
        float lo = 1e30f, hi = -1e30f;
        #pragma unroll
        for (int m = 0; m < Mz; m++) {
          float ks = expf(phis[m]);
          float be = expf(phis[Mz + m]);
          prm[m]        = ks;
          prm[Mz + m]   = expf(-phis[Mz + m]);   // 1/beta
          prm[2*Mz + m] = ae[m] / ssum;
          lo = fminf(lo, ks - 0.5f - 25.f*be);   // sig(-25) < fp32 visibility
          hi = fmaxf(hi, ks + 0.5f + 25.f*be);
        }
        int llo = lo > 0.f ? (int)floorf(lo) : 0;
        if (llo > Lz) llo = Lz;
        int lhi = hi < (float)Lz ? (int)ceilf(hi) + 1 : Lz;
        if (lhi > Lz) lhi = Lz;
        rng[0] = llo; rng[1] = lhi;
      }
      HSYNC(1, tgt);
      const int llo = rng[0], lhi = rng[1];
      // w(t-1) on active range (256 threads)
      for (int l = llo + t2; l < lhi; l += 256) {
        float u = (float)l;
        float t1 = 0.f, t0 = 0.f;
        #pragma unroll
        for (int m = 0; m < Mz; m++) {
          float ks = prm[m], ib = prm[Mz + m], al = prm[2*Mz + m];
          t1 += al * fsig((u + 0.5f - ks) * ib);
          t0 += al * fsig((u - 0.5f - ks) * ib);
        }
        wsm[l] = t1 - t0;
      }
      HSYNC(2, tgt);
      // gctx(t) for own 512-j slice: thread owns one u32 col (2 j)
      {
        const int g = t2 >> 6, jj2 = t2 & 63;
        const int col = (g << 8) + (q << 6) + jj2;
        const u32* m2c = M2u + (((size_t)b << 10) << 10) + col;
        float alo0 = 0.f, ahi0 = 0.f, alo1 = 0.f, ahi1 = 0.f;
        int l = llo;
        for (; l + 1 < lhi; l += 2) {
          float w0 = wsm[l], w1 = wsm[l+1];
          u32 v0 = m2c[(size_t)l << 10];
          u32 v1 = m2c[(size_t)(l+1) << 10];
          alo0 = fmaf(w0, lo16(v0), alo0); ahi0 = fmaf(w0, hi16(v0), ahi0);
          alo1 = fmaf(w1, lo16(v1), alo1); ahi1 = fmaf(w1, hi16(v1), ahi1);
        }
        if (l < lhi) {
          float w0 = wsm[l]; u32 v0 = m2c[(size_t)l << 10];
          alo0 = fmaf(w0, lo16(v0), alo0); ahi0 = fmaf(w0, hi16(v0), ahi0);
        }
        gctxl[(g << 7) + 2*jj2]     = alo0 + alo1;
        gctxl[(g << 7) + 2*jj2 + 1] = ahi0 + ahi1;
      }
      // align(t-1) (q==0 only; inside tail, overlapped with GEMV)
      if (q == 0) {
        for (int l = llo + t2; l < lhi; l += 256)
          align_out[((size_t)b*Tz + (t-1))*Lz + l] = wsm[l];
      }
    }
    __syncthreads();   // join

    // ======== LSTM(t): d in [128q,128q+128), gate order i,f,g,o
    if (tid < 128) {
      const int dl = tid;
      u32 xwp[4] = {xwp0, xwp1, xwp2, xwp3};
      float gv[4];
      #pragma unroll
      for (int g = 0; g < 4; ++g) {
        int pos = (g << 7) + dl;
        float s = pgemv[0][pos] + pgemv[1][pos] + gctxl[pos];
        s += (dl & 1) ? hi16(xwp[g]) : lo16(xwp[g]);
        gv[g] = s;
      }
      float ig = fsig(gv[0]);
      float fg = fsig(gv[1]);
      float gg = tanhf(gv[2]);
      float og = fsig(gv[3]);
      float cn = fg*cs[dl] + ig*gg;
      float hn = og*tanhf(cn);
      cs[dl] = cn;
      hf[(q << 7) + dl] = hn;
      st_rlxf(&hx[(((t & 1)*Bz + b)*NBQ + q)*128 + dl], hn);
    }
    VWAIT();
    __syncthreads();
    if (tid == 0) st_rlx(&fQ[(b*NBQ + q)*FP], t+1);

    // poll siblings, gather their h-quarters, pack for next GEMV
    if (tid < NBQ) {
      while (ld_rlx(&fQ[(b*NBQ + tid)*FP]) < t+1) __builtin_amdgcn_s_sleep(1);
    }
    __syncthreads();
    if (tid < 384) {
      int rp = tid >> 7;
      int p = rp + (rp >= q ? 1 : 0);
      int dl2 = tid & 127;
      hf[(p << 7) + dl2] = ld_rlxf(&hx[(((t & 1)*Bz + b)*NBQ + p)*128 + dl2]);
    }
    __syncthreads();
    if (tid < 256) xp[tid] = pack16(hf[2*tid], hf[2*tid+1]);
    __syncthreads();
  }

  // ======== post-loop: TAIL(T-1) + outputs, q==0 only, full block ========
  if (q != 0) return;
  if (tid < 16*3*Mz) {
    int m = tid >> 4, l16 = tid & 15;
    const float4* wr = reinterpret_cast<const float4*>(W_g + m*Dz);
    const float4* hr = reinterpret_cast<const float4*>(hf);
    float s = 0.f;
    #pragma unroll
    for (int i = 0; i < 8; i++) {
      float4 wv = wr[l16 + (i<<4)];
      float4 hv = hr[l16 + (i<<4)];
      s += wv.x*hv.x + wv.y*hv.y + wv.z*hv.z + wv.w*hv.w;
    }
    s += __shfl_xor(s, 1);
    s += __shfl_xor(s, 2);
    s += __shfl_xor(s, 4);
    s += __shfl_xor(s, 8);
    if (l16 == 0) phis[m] = s + b_g[m];
  }
  __syncthreads();
  if (tid == 0) {
    float mx = -1e30f;
    #pragma unroll
    for (int m = 0; m < Mz; m++) mx = fmaxf(mx, phis[2*Mz + m]);
    float ae[Mz], ssum = 0.f;
    #pragma unroll
    for (int m = 0; m < Mz; m++) { ae[m] = expf(phis[2*Mz + m] - mx); ssum += ae[m]; }
    float lo = 1e30f, hi = -1e30f;
    #pragma unroll
    for (int m = 0; m < Mz; m++) {
      float ks = expf(phis[m]);
      float be = expf(phis[Mz + m]);
      prm[m]        = ks;
      prm[Mz + m]   = expf(-phis[Mz + m]);
      prm[2*Mz + m] = ae[m] / ssum;
      lo = fminf(lo, ks - 0.5f - 25.f*be);
      hi = fmaxf(hi, ks + 0.5f + 25.f*be);
    }
    int llo = lo > 0.f ? (int)floorf(lo) : 0;
    if (llo > Lz) llo = Lz;
    int lhi = hi < (float)Lz ? (int)ceilf(hi) + 1 : Lz;
    if (lhi > Lz) lhi = Lz;
    rng[0] = llo; rng[1] = lhi;
  }
  __syncthreads();
  const int llo = rng[0], lhi = rng[1];
  for (int l = llo + tid; l < lhi; l += 512) {
    float u = (float)l;
    float t1 = 0.f, t0 = 0.f;
    #pragma unroll
    for (int m = 0; m < Mz; m++) {
      float ks = prm[m], ib = prm[Mz + m], al = prm[2*Mz + m];
      t1 += al * fsig((u + 0.5f - ks) * ib);
      t0 += al * fsig((u - 0.5f - ks) * ib);
    }
    float w = t1 - t0;
    wsm[l] = w;
    align_out[((size_t)b*Tz + (Tz-1))*Lz + l] = w;
  }
  __syncthreads();
  {
    const int grp = tid >> 7, d0 = (tid & 127) << 2;
    const float* mb = memory + (size_t)b*Lz*Dz + d0;
    float4 a = make_float4(0.f, 0.f, 0.f, 0.f);
    for (int l = llo + grp; l < lhi; l += 4) {
      float wl = wsm[l];
      float4 m0 = *reinterpret_cast<const float4*>(&mb[(size_t)l*Dz]);
      a.x = fmaf(wl, m0.x, a.x); a.y = fmaf(wl, m0.y, a.y);
      a.z = fmaf(wl, m0.z, a.z); a.w = fmaf(wl, m0.w, a.w);
    }
    *reinterpret_cast<float4*>(&pgemv[grp][d0]) = a;
  }
  __syncthreads();
  ctx_out[b*Dz + tid] = pgemv[0][tid] + pgemv[1][tid] + pgemv[2][tid] + pgemv[3][tid];
  if (tid == 0) {
    float u = (float)(lens[b] - 1);
    float t1 = 0.f;
    #pragma unroll
    for (int m = 0; m < Mz; m++)
      t1 += prm[2*Mz + m] * fsig((u + 0.5f - prm[m]) * prm[Mz + m]);
    term_out[b] = 1.0f - t1;
  }
}

// ================= fallback (small ws): two-kernel loop path =================
__global__ __launch_bounds__(256) void k_gemm(
    const float* __restrict__ x_all, const float* __restrict__ ctxs,
    const float* __restrict__ h, const float* __restrict__ W_ih,
    const float* __restrict__ W_hh, float* __restrict__ partial, int t)
{
  __shared__ float Xs[Bz][130];
  __shared__ float Wt[128][130];
  const int jt = blockIdx.x, kcb = blockIdx.y;
  const int j0 = jt*128, k0 = kcb*128;
  const int tid = threadIdx.x;
  for (int i = tid; i < Bz*128; i += 256) {
    int bb = i >> 7, kk = i & 127;
    int k = k0 + kk;
    float v;
    if (k < Dz)        v = x_all[((size_t)bb*Tz + t)*Dz + k];
    else if (k < 2*Dz) v = ctxs[bb*Dz + (k - Dz)];
    else               v = h[bb*Dz + (k - 2*Dz)];
    Xs[bb][kk] = v;
  }
  {
    const float* Wsrc; int ldw, col0;
    if (k0 < 2*Dz) { Wsrc = W_ih; ldw = 2*Dz; col0 = k0; }
    else           { Wsrc = W_hh; ldw = Dz;   col0 = k0 - 2*Dz; }
    for (int i = tid; i < 128*32; i += 256) {
      int jj = i >> 5, k4 = (i & 31) << 2;
      float4 v = *reinterpret_cast<const float4*>(&Wsrc[(size_t)(j0 + jj)*ldw + col0 + k4]);
      Wt[jj][k4] = v.x; Wt[jj][k4+1] = v.y; Wt[jj][k4+2] = v.z; Wt[jj][k4+3] = v.w;
    }
  }
  __syncthreads();
  const int jg = tid & 31, bg = tid >> 5;
  const int bl = bg << 2;
  float acc[4][4] = {};
  #pragma unroll 4
  for (int k = 0; k < 128; k += 2) {
    float2 xv[4], wv[4];
    #pragma unroll
    for (int b2 = 0; b2 < 4; b2++)
      xv[b2] = *reinterpret_cast<const float2*>(&Xs[bl + b2][k]);
    #pragma unroll
    for (int jj = 0; jj < 4; jj++)
      wv[jj] = *reinterpret_cast<const float2*>(&Wt[jg + (jj << 5)][k]);
    #pragma unroll
    for (int jj = 0; jj < 4; jj++)
      #pragma unroll
      for (int b2 = 0; b2 < 4; b2++)
        acc[jj][b2] += wv[jj].x * xv[b2].x + wv[jj].y * xv[b2].y;
  }
  #pragma unroll
  for (int jj = 0; jj < 4; jj++)
    #pragma unroll
    for (int b2 = 0; b2 < 4; b2++)
      partial[((size_t)kcb*Bz + (bl + b2))*G4D + j0 + jg + (jj << 5)] = acc[jj][b2];
}

__global__ __launch_bounds__(512) void k_fused(
    const float* __restrict__ partial, const float* __restrict__ b_ih,
    const float* __restrict__ b_hh,
    float* __restrict__ h, float* __restrict__ c,
    const float* __restrict__ W_g, const float* __restrict__ b_g,
    const float* __restrict__ memory, const int* __restrict__ lens,
    float* __restrict__ ctxs, float* __restrict__ ctx_out,
    float* __restrict__ align_out, float* __restrict__ term_out,
    int t, int final_, int nkc)
{
  const int b = blockIdx.x, tid = threadIdx.x;
  __shared__ float4 gs4[G4D/4];
  __shared__ float hsb[Dz];
  __shared__ float phis[3*Mz];
  __shared__ float prm[3*Mz];
  __shared__ float wsm[Lz];
  __shared__ int   rng[2];
  float* gs = (float*)gs4;
  {
    int j = 4*tid;
    float4 bi = *reinterpret_cast<const float4*>(&b_ih[j]);
    float4 bh = *reinterpret_cast<const float4*>(&b_hh[j]);
    float4 s = make_float4(bi.x+bh.x, bi.y+bh.y, bi.z+bh.z, bi.w+bh.w);
    const float4* pp = reinterpret_cast<const float4*>(partial) + (size_t)b*(G4D/4) + tid;
    for (int kcb = 0; kcb < nkc; kcb++) {
      float4 p = pp[(size_t)kcb*Bz*(G4D/4)];
      s.x += p.x; s.y += p.y; s.z += p.z; s.w += p.w;
    }
    gs4[tid] = s;
  }
  __syncthreads();
  {
    const int d = tid;
    float ig = 1.0f / (1.0f + expf(-gs[d]));
    float fg = 1.0f / (1.0f + expf(-gs[Dz + d]));
    float gg = tanhf(gs[2*Dz + d]);
    float og = 1.0f / (1.0f + expf(-gs[3*Dz + d]));
    float cn = fg * c[b*Dz + d] + ig * gg;
    float hn = og * tanhf(cn);
    c[b*Dz + d] = cn;
    h[b*Dz + d] = hn;
    hsb[d] = hn;
  }
  __syncthreads();
  if (tid < 16*3*Mz) {
    int m = tid >> 4, l16 = tid & 15;
    float s = 0.f;
    #pragma unroll 4
    for (int k = l16; k < Dz; k += 16) s += W_g[m*Dz + k] * hsb[k];
    s += __shfl_xor(s, 1);
    s += __shfl_xor(s, 2);
    s += __shfl_xor(s, 4);
    s += __shfl_xor(s, 8);
    if (l16 == 0) phis[m] = s + b_g[m];
  }
  __syncthreads();
  if (tid == 0) {
    float mx = -1e30f;
    #pragma unroll
    for (int m = 0; m < Mz; m++) mx = fmaxf(mx, phis[2*Mz + m]);
    float ae[Mz], ssum = 0.f;
    #pragma unroll
    for (int m = 0; m < Mz; m++) { ae[m] = expf(phis[2*Mz + m] - mx); ssum += ae[m]; }
    float lo = 1e30f, hi = -1e30f;
    #pragma unroll
    for (int m = 0; m < Mz; m++) {
      float ks = expf(phis[m]);
      float be = expf(phis[Mz + m]);
      prm[m]        = ks;
      prm[Mz + m]   = expf(-phis[Mz + m]);
      prm[2*Mz + m] = ae[m] / ssum;
      lo = fminf(lo, ks - 0.5f - 25.f*be);
      hi = fmaxf(hi, ks + 0.5f + 25.f*be);
    }
    int llo = lo > 0.f ? (int)floorf(lo) : 0;
    if (llo > Lz) llo = Lz;
    int lhi = hi < (float)Lz ? (int)ceilf(hi) + 1 : Lz;
    if (lhi > Lz) lhi = Lz;
    rng[0] = llo; rng[1] = lhi;
  }
  __syncthreads();
  const int llo = rng[0], lhi = rng[1];
  for (int l = llo + tid; l < lhi; l += 512) {
    float u = (float)l;
    float t1 = 0.f, t0 = 0.f;
    #pragma unroll
    for (int m = 0; m < Mz; m++) {
      float ks = prm[m], ib = prm[Mz + m], al = prm[2*Mz + m];
      t1 += al * fsig((u + 0.5f - ks) * ib);
      t0 += al * fsig((u - 0.5f - ks) * ib);
    }
    float w = t1 - t0;
    wsm[l] = w;
    align_out[((size_t)b*Tz + t)*Lz + l] = w;
  }
  __syncthreads();
  {
    const float* mb = memory + (size_t)b*Lz*Dz + tid;
    float acc = 0.f;
    #pragma unroll 4
    for (int l = llo; l < lhi; l++)
      acc += wsm[l] * mb[(size_t)l*Dz];
    ctxs[b*Dz + tid] = acc;
    if (final_) ctx_out[b*Dz + tid] = acc;
  }
  if (final_ && tid == 0) {
    float u = (float)(lens[b] - 1);
    float t1 = 0.f;
    #pragma unroll
    for (int m = 0; m < Mz; m++)
      t1 += prm[2*Mz + m] * fsig((u + 0.5f - prm[m]) * prm[Mz + m]);
    term_out[b] = 1.0f - t1;
  }
}

extern "C" void kernel_launch(void* const* d_in, const int* in_sizes, int n_in,
                              void* d_out, int out_size, void* d_ws, size_t ws_size,
                              hipStream_t stream)
{
  (void)in_sizes; (void)n_in; (void)out_size;
  const float* x    = (const float*)d_in[0];
  const float* mem  = (const float*)d_in[1];
  const int*   lens = (const int*)d_in[2];
  const float* W_ih = (const float*)d_in[3];
  const float* W_hh = (const float*)d_in[4];
  const float* b_ih = (const float*)d_in[5];
  const float* b_hh = (const float*)d_in[6];
  const float* W_g  = (const float*)d_in[7];
  const float* b_g  = (const float*)d_in[8];

  float* out = (float*)d_out;
  float* ctx_out   = out;                                  // [B,1,D]
  float* align_out = out + Bz*Dz;                          // [B,T,L]
  float* term_out  = out + Bz*Dz + (size_t)Bz*Tz*Lz;       // [B,1]

  const size_t needP = (size_t)NEED_I * sizeof(int);

  hipMemsetAsync(align_out, 0, (size_t)Bz*Tz*Lz*sizeof(float), stream);

  if (ws_size >= needP) {
    int*   ip  = (int*)d_ws;
    int*   fQ  = ip + OFF_FQ;
    float* hx  = (float*)(ip + OFF_HX);
    u32*   Wq  = (u32*)(ip + OFF_WQ);
    u32*   M2u = (u32*)(ip + OFF_M2);
    u32*   xwu = (u32*)(ip + OFF_XW);

    hipMemsetAsync(d_ws, 0, (size_t)OFF_HX * sizeof(int), stream);  // flags only
    k_pre<<<dim3((Bz*Tz)/PM, G4D/PN), 256, 0, stream>>>(x, W_ih, b_ih, b_hh, xwu);
    k_m2<<<dim3(16, 16), 512, 0, stream>>>(mem, W_ih, M2u);
    k_packh<<<256, 512, 0, stream>>>(W_hh, Wq);
    k_persist<<<NBLK, 512, 0, stream>>>(mem, lens, W_g, b_g, xwu, M2u, Wq,
                                        hx, fQ, ctx_out, align_out, term_out);
  } else {
    float* wsf     = (float*)d_ws;
    float* h       = wsf;
    float* c       = h + Bz*Dz;
    float* ctxs    = c + Bz*Dz;
    float* partial = ctxs + Bz*Dz;               // [12][B][4D]
    hipMemsetAsync(d_ws, 0, (size_t)(3*Bz*Dz)*sizeof(float), stream);
    for (int t = 0; t < Tz; t++) {
      k_gemm<<<dim3(G4D/128, 12), 256, 0, stream>>>(x, ctxs, h, W_ih, W_hh, partial, t);
      k_fused<<<Bz, 512, 0, stream>>>(partial, b_ih, b_hh, h, c, W_g, b_g,
                                      mem, lens, ctxs, ctx_out, align_out, term_out,
                                      t, t == Tz-1, 12);
    }
  }
}

// Round 17
// 5774.892 us; speedup vs baseline: 1.1635x; 1.0437x over previous
//
#include <hip/hip_runtime.h>

#define Bz 32
#define Tz 512
#define Dz 512
#define Lz 1024
#define Mz 10
#define G4D 2048
#define FP 32
#define NBQ 8                 // blocks per batch
#define NBLK (Bz*NBQ)         // 256
// ws int-region offsets
#define OFF_FQ   0                        // fQ[32][8][FP] = 8192
#define OFF_HX   8192                     // hx[2][32][512] f32 = 32768
#define OFF_WQ   40960                    // Wq[8][256][256] u32 = 524288 (2MB)
#define OFF_M2   565248                   // M2[32768][1024] u32 = 128MB
#define OFF_XW   34119680                 // xw[16384][1024] u32 = 64MB
#define NEED_I   50896896
// k_pre tiles
#define PM 128
#define PN 128
#define PK 32

typedef unsigned long long u64;
typedef unsigned u32;
typedef _Float16 f16x8 __attribute__((ext_vector_type(8)));
typedef float f32x4 __attribute__((ext_vector_type(4)));
typedef _Float16 half2_t __attribute__((ext_vector_type(2)));

#if defined(__has_builtin)
#if __has_builtin(__builtin_amdgcn_fdot2)
#define HAS_FDOT2 1
#endif
#endif

__device__ __forceinline__ float fsig(float x) { return 1.0f / (1.0f + __expf(-x)); }
__device__ __forceinline__ int ld_rlx(const int* p) {
  return __hip_atomic_load(p, __ATOMIC_RELAXED, __HIP_MEMORY_SCOPE_AGENT);
}
__device__ __forceinline__ void st_rlx(int* p, int v) {
  __hip_atomic_store(p, v, __ATOMIC_RELAXED, __HIP_MEMORY_SCOPE_AGENT);
}
__device__ __forceinline__ float ld_rlxf(const float* p) {
  return __hip_atomic_load(p, __ATOMIC_RELAXED, __HIP_MEMORY_SCOPE_AGENT);
}
__device__ __forceinline__ void st_rlxf(float* p, float v) {
  __hip_atomic_store(p, v, __ATOMIC_RELAXED, __HIP_MEMORY_SCOPE_AGENT);
}
__device__ __forceinline__ u32 pack16(float a, float b) {
  unsigned short la = __builtin_bit_cast(unsigned short, (_Float16)a);
  unsigned short lb = __builtin_bit_cast(unsigned short, (_Float16)b);
  return (u32)la | ((u32)lb << 16);
}
__device__ __forceinline__ float lo16(u32 v) {
  return (float)__builtin_bit_cast(half2_t, v)[0];
}
__device__ __forceinline__ float hi16(u32 v) {
  return (float)__builtin_bit_cast(half2_t, v)[1];
}
__device__ __forceinline__ float dot2f(u32 xu, u32 wu, float acc) {
  half2_t xh = __builtin_bit_cast(half2_t, xu);
  half2_t wh = __builtin_bit_cast(half2_t, wu);
#ifdef HAS_FDOT2
  return __builtin_amdgcn_fdot2(xh, wh, acc, false);
#else
  return acc + (float)xh[0]*(float)wh[0] + (float)xh[1]*(float)wh[1];
#endif
}
#define VWAIT() asm volatile("s_waitcnt vmcnt(0)" ::: "memory")

// ---------------- K0 (once): xw_f16[bt][j] = x[bt,:].W_ih[j,0:512] + b_ih[j] + b_hh[j] ----------------
__global__ __launch_bounds__(256) void k_pre(
    const float* __restrict__ x, const float* __restrict__ W_ih,
    const float* __restrict__ b_ih, const float* __restrict__ b_hh,
    u32* __restrict__ xwu)
{
  __shared__ float As[PM][PK+1];
  __shared__ float Bs[PN][PK+1];
  const int m0 = blockIdx.x*PM, n0 = blockIdx.y*PN;
  const int tid = threadIdx.x;
  const int mg = tid >> 4, ng = tid & 15;
  float acc[8][8] = {};
  for (int k0 = 0; k0 < Dz; k0 += PK) {
    for (int i = tid; i < PM*(PK/4); i += 256) {
      int row = i >> 3, c4 = (i & 7) << 2;
      float4 v = *reinterpret_cast<const float4*>(&x[(size_t)(m0+row)*Dz + k0 + c4]);
      As[row][c4] = v.x; As[row][c4+1] = v.y; As[row][c4+2] = v.z; As[row][c4+3] = v.w;
    }
    for (int i = tid; i < PN*(PK/4); i += 256) {
      int row = i >> 3, c4 = (i & 7) << 2;
      float4 v = *reinterpret_cast<const float4*>(&W_ih[(size_t)(n0+row)*(2*Dz) + k0 + c4]);
      Bs[row][c4] = v.x; Bs[row][c4+1] = v.y; Bs[row][c4+2] = v.z; Bs[row][c4+3] = v.w;
    }
    __syncthreads();
    #pragma unroll 8
    for (int k = 0; k < PK; k++) {
      float a8[8], b8[8];
      #pragma unroll
      for (int r = 0; r < 8; r++) a8[r] = As[mg*8+r][k];
      #pragma unroll
      for (int s = 0; s < 8; s++) b8[s] = Bs[ng*8+s][k];
      #pragma unroll
      for (int r = 0; r < 8; r++)
        #pragma unroll
        for (int s = 0; s < 8; s++) acc[r][s] += a8[r]*b8[s];
    }
    __syncthreads();
  }
  const int nb = n0 + ng*8;
  #pragma unroll
  for (int r = 0; r < 8; r++) {
    int m = m0 + mg*8 + r;
    #pragma unroll
    for (int s2 = 0; s2 < 4; s2++) {
      int n = nb + 2*s2;
      xwu[(size_t)m*1024 + (n >> 1)] =
          pack16(acc[r][2*s2]   + b_ih[n]   + b_hh[n],
                 acc[r][2*s2+1] + b_ih[n+1] + b_hh[n+1]);
    }
  }
}

// ---------------- K1 (once): M2[m][j] = memory[m,:] . W_ic[j,:]  (f16 pairs, MFMA) ----------------
__global__ __launch_bounds__(512) void k_m2(
    const float* __restrict__ memory, const float* __restrict__ W_ih,
    u32* __restrict__ M2u)
{
  __shared__ __align__(16) u32 smem[149760/4];
  u32* Bs = smem;              // [128][260]
  u32* As = smem + 33280;      // [16][260]
  const int tid = threadIdx.x;
  const int n0 = blockIdx.x * 128, mc = blockIdx.y;
  for (int i = tid; i < 128*256; i += 512) {
    int jl = i >> 8, ku = i & 255;
    float2 wv = *reinterpret_cast<const float2*>(&W_ih[(size_t)(n0+jl)*(2*Dz) + 512 + 2*ku]);
    Bs[jl*260 + (ku ^ ((jl & 7) << 2))] = pack16(wv.x, wv.y);
  }
  __syncthreads();
  const int w = tid >> 6, lane = tid & 63;
  const int fr = lane & 15, kq = (lane >> 4) << 2;
  const int frsw = (fr & 7) << 2;
  for (int mt = 0; mt < 128; ++mt) {
    const int m0 = mc*2048 + mt*16;
    for (int i = tid; i < 16*256; i += 512) {
      int r = i >> 8, ku = i & 255;
      float2 mv = *reinterpret_cast<const float2*>(&memory[(size_t)(m0+r)*Dz + 2*ku]);
      As[r*260 + (ku ^ ((r & 7) << 2))] = pack16(mv.x, mv.y);
    }
    __syncthreads();
    f32x4 acc = {0.f, 0.f, 0.f, 0.f};
    #pragma unroll
    for (int ks = 0; ks < 16; ++ks) {
      int col = (kq + ks*16) ^ frsw;
      f16x8 av = *reinterpret_cast<const f16x8*>(As + fr*260 + col);
      f16x8 bv = *reinterpret_cast<const f16x8*>(Bs + (w*16 + fr)*260 + col);
      acc = __builtin_amdgcn_mfma_f32_16x16x32_f16(av, bv, acc, 0, 0, 0);
    }
    #pragma unroll
    for (int i = 0; i < 4; ++i) {
      float oth = __shfl_xor(acc[i], 1);
      if (!(lane & 1)) {
        int m = m0 + ((lane >> 4) << 2) + i;
        int j = n0 + w*16 + fr;
        M2u[(size_t)m*1024 + (j >> 1)] = pack16(acc[i], oth);
      }
    }
    __syncthreads();
  }
}

// ---------------- K2 (once): Wq[q][kp][pos] = pack(Whh[j][2kp], Whh[j][2kp+1]) ----------------
// pos = g*64 + jj ; j = 512*g + 64*q + jj   (slice q = gate rows for d in [64q,64q+64))
__global__ __launch_bounds__(512) void k_packh(
    const float* __restrict__ W_hh, u32* __restrict__ Wq)
{
  const int kp = blockIdx.x;
  for (int idx = threadIdx.x; idx < 2048; idx += 512) {
    int q = idx >> 8, pos = idx & 255;
    int g = pos >> 6, jj = pos & 63;
    int j = 512*g + 64*q + jj;
    float2 wv = *reinterpret_cast<const float2*>(&W_hh[(size_t)j*Dz + 2*kp]);
    Wq[(size_t)q*65536 + kp*256 + pos] = pack16(wv.x, wv.y);
  }
}

// ---- intra-tail-half sync: monotonic LDS counters, 4 tail-wave leaders each ----
#define HSYNC(id, tgt) do {                                                    \
  __threadfence_block();                                                       \
  if ((tid & 63) == 0) atomicAdd(&scnt[id], 1);                                \
  while (__hip_atomic_load(&scnt[id], __ATOMIC_RELAXED,                        \
                           __HIP_MEMORY_SCOPE_WORKGROUP) < (tgt))              \
    __builtin_amdgcn_s_sleep(1);                                               \
  __threadfence_block();                                                       \
} while (0)

// ---------------- Persistent kernel: wave-specialized GEMV || TAIL, 8 blocks/batch ----------------
__global__ __launch_bounds__(512) void k_persist(
    const float* __restrict__ memory, const int* __restrict__ lens,
    const float* __restrict__ W_g,  const float* __restrict__ b_g,
    const u32* __restrict__ xwu, const u32* __restrict__ M2u,
    const u32* __restrict__ Wq,
    float* __restrict__ hx, int* __restrict__ fQ,
    float* __restrict__ ctx_out, float* __restrict__ align_out,
    float* __restrict__ term_out)
{
  const int blk = blockIdx.x, tid = threadIdx.x;
  const int b = blk >> 3, q = blk & 7;

  __shared__ float pgemv[4][512];     // GEMV uses [4][256]; post-loop einsum [4][512]
  __shared__ float gctxl[256];        // ctx gate contribution for own 256 gate rows
  __shared__ float wsm[Lz];
  __shared__ float hf[Dz];
  __shared__ float cs[64];
  __shared__ u32   xp[256];
  __shared__ float phis[3*Mz], prm[3*Mz];
  __shared__ int   rng[2];
  __shared__ int   scnt[3];

  if (tid < 64)  cs[tid] = 0.f;
  if (tid < 256) { xp[tid] = 0u; gctxl[tid] = 0.f; }   // h(-1)=ctx(-1)=0
  if (tid < 3)   scnt[tid] = 0;
  __syncthreads();

  const uint4* wq4 = reinterpret_cast<const uint4*>(Wq) + (size_t)q*16384;

  for (int t = 0; t < Tz; ++t) {
    // prefetch xw gate biases for LSTM(t) (hidden under GEMV)
    u32 xwp0 = 0, xwp1 = 0, xwp2 = 0, xwp3 = 0;
    if (tid < 64) {
      const size_t xwb = ((size_t)(b*Tz + t)) << 10;
      const int o = (q << 5) + (tid >> 1);
      xwp0 = xwu[xwb + o];
      xwp1 = xwu[xwb + 256 + o];
      xwp2 = xwu[xwb + 512 + o];
      xwp3 = xwu[xwb + 768 + o];
    }

    if (tid < 256) {
      // ======== GEMV half (waves 0-3): own 256 gate rows, K=512, from xp=h(t-1)
      const int kg2 = tid >> 6, tq2 = tid & 63;
      const uint4* wr = wq4 + tq2;
      float a0 = 0.f, a1 = 0.f, a2 = 0.f, a3 = 0.f;
      const int k0 = kg2 << 6;
      #pragma unroll 4
      for (int kp = k0; kp < k0 + 64; ++kp) {
        uint4 wv = wr[(size_t)kp << 6];
        u32 xv = xp[kp];
        a0 = dot2f(xv, wv.x, a0);
        a1 = dot2f(xv, wv.y, a1);
        a2 = dot2f(xv, wv.z, a2);
        a3 = dot2f(xv, wv.w, a3);
      }
      *reinterpret_cast<float4*>(&pgemv[kg2][tq2 << 2]) = make_float4(a0, a1, a2, a3);
    } else if (t > 0) {
      // ======== TAIL half (waves 4-7): derived from h(t-1)
      const int t2 = tid - 256;
      const int tgt = 4 * t;
      if (t2 < 8*3*Mz) {
        int m = t2 >> 3, l8 = t2 & 7;
        const float4* wr2 = reinterpret_cast<const float4*>(W_g + m*Dz);
        const float4* hr = reinterpret_cast<const float4*>(hf);
        float s = 0.f;
        #pragma unroll
        for (int i = 0; i < 16; i++) {
          float4 wv = wr2[l8 + (i << 3)];
          float4 hv = hr[l8 + (i << 3)];
          s += wv.x*hv.x + wv.y*hv.y + wv.z*hv.z + wv.w*hv.w;
        }
        s += __shfl_xor(s, 1);
        s += __shfl_xor(s, 2);
        s += __shfl_xor(s, 4);
        if (l8 == 0) phis[m] = s + b_g[m];
      }
      HSYNC(0, tgt);
      if (t2 == 0) {
        float mx = -1e30f;
        #pragma unroll
        for (int m = 0; m < Mz; m++) mx = fmaxf(mx, phis[2*Mz + m]);
        float ae[Mz], ssum = 0.f;
        #pragma unroll
        for (int m = 0; m < Mz; m++) { ae[m] = expf(phis[2*Mz + m] - mx); ssum += ae[m]; }
        float lo = 1e30f, hi = -1e30f;
        #pragma unroll
        for (int m = 0; m < Mz; m++) {
          float ks = expf(phis[m]);
          float be = expf(phis[Mz + m]);
          prm[m]        = ks;
          prm[Mz + m]   = expf(-phis[Mz + m]);   // 1/beta
          prm[2*Mz + m] = ae[m] / ssum;
          lo = fminf(lo, ks - 0.5f - 25.f*be);   // sig(-25) < fp32 visibility
          hi = fmaxf(hi, ks + 0.5f + 25.f*be);
        }
        int llo = lo > 0.f ? (int)floorf(lo) : 0;
        if (llo > Lz) llo = Lz;
        int lhi = hi < (float)Lz ? (int)ceilf(hi) + 1 : Lz;
        if (lhi > Lz) lhi = Lz;
        rng[0] = llo; rng[1] = lhi;
      }
      HSYNC(1, tgt);
      const int llo = rng[0], lhi = rng[1];
      for (int l = llo + t2; l < lhi; l += 256) {
        float u = (float)l;
        float t1 = 0.f, t0 = 0.f;
        #pragma unroll
        for (int m = 0; m < Mz; m++) {
          float ks = prm[m], ib = prm[Mz + m], al = prm[2*Mz + m];
          t1 += al * fsig((u + 0.5f - ks) * ib);
          t0 += al * fsig((u - 0.5f - ks) * ib);
        }
        wsm[l] = t1 - t0;
      }
      HSYNC(2, tgt);
      // gctx(t) for own 256 gate rows: 128 u32 cols, 1 per thread (t2<128)
      if (t2 < 128) {
        const int g = t2 >> 5, jc2 = t2 & 31;
        const int col = (g << 8) + (q << 5) + jc2;
        const u32* m2c = M2u + (((size_t)b << 10) << 10) + col;
        float alo0 = 0.f, ahi0 = 0.f, alo1 = 0.f, ahi1 = 0.f;
        int l = llo;
        for (; l + 1 < lhi; l += 2) {
          float w0 = wsm[l], w1 = wsm[l+1];
          u32 v0 = m2c[(size_t)l << 10];
          u32 v1 = m2c[(size_t)(l+1) << 10];
          alo0 = fmaf(w0, lo16(v0), alo0); ahi0 = fmaf(w0, hi16(v0), ahi0);
          alo1 = fmaf(w1, lo16(v1), alo1); ahi1 = fmaf(w1, hi16(v1), ahi1);
        }
        if (l < lhi) {
          float w0 = wsm[l]; u32 v0 = m2c[(size_t)l << 10];
          alo0 = fmaf(w0, lo16(v0), alo0); ahi0 = fmaf(w0, hi16(v0), ahi0);
        }
        gctxl[(g << 6) + 2*jc2]     = alo0 + alo1;
        gctxl[(g << 6) + 2*jc2 + 1] = ahi0 + ahi1;
      }
      // align(t-1) (q==0 only; overlapped with GEMV)
      if (q == 0) {
        for (int l = llo + t2; l < lhi; l += 256)
          align_out[((size_t)b*Tz + (t-1))*Lz + l] = wsm[l];
      }
    }
    __syncthreads();   // join

    // ======== LSTM(t): d in [64q, 64q+64), gate order i,f,g,o
    if (tid < 64) {
      const int dl = tid;
      u32 xwp[4] = {xwp0, xwp1, xwp2, xwp3};
      float gv[4];
      #pragma unroll
      for (int g = 0; g < 4; ++g) {
        int pos = (g << 6) + dl;
        float s = pgemv[0][pos] + pgemv[1][pos] + pgemv[2][pos] + pgemv[3][pos]
                + gctxl[pos];
        s += (dl & 1) ? hi16(xwp[g]) : lo16(xwp[g]);
        gv[g] = s;
      }
      float ig = fsig(gv[0]);
      float fg = fsig(gv[1]);
      float gg = tanhf(gv[2]);
      float og = fsig(gv[3]);
      float cn = fg*cs[dl] + ig*gg;
      float hn = og*tanhf(cn);
      cs[dl] = cn;
      hf[(q << 6) + dl] = hn;
      st_rlxf(&hx[((t & 1)*Bz + b)*512 + (q << 6) + dl], hn);
    }
    VWAIT();
    __syncthreads();
    if (tid == 0) st_rlx(&fQ[(b*NBQ + q)*FP], t+1);

    // poll siblings, gather their h-slices, pack for next GEMV
    if (tid < NBQ) {
      while (ld_rlx(&fQ[(b*NBQ + tid)*FP]) < t+1) __builtin_amdgcn_s_sleep(1);
    }
    __syncthreads();
    if (tid < 448) {
      int rp = tid >> 6;
      int p = rp + (rp >= q ? 1 : 0);
      int dl2 = tid & 63;
      hf[(p << 6) + dl2] = ld_rlxf(&hx[((t & 1)*Bz + b)*512 + (p << 6) + dl2]);
    }
    __syncthreads();
    if (tid < 256) xp[tid] = pack16(hf[2*tid], hf[2*tid+1]);
    __syncthreads();
  }

  // ======== post-loop: TAIL(T-1) + outputs, q==0 only, full block ========
  if (q != 0) return;
  if (tid < 16*3*Mz) {
    int m = tid >> 4, l16 = tid & 15;
    const float4* wr = reinterpret_cast<const float4*>(W_g + m*Dz);
    const float4* hr = reinterpret_cast<const float4*>(hf);
    float s = 0.f;
    #pragma unroll
    for (int i = 0; i < 8; i++) {
      float4 wv = wr[l16 + (i<<4)];
      float4 hv = hr[l16 + (i<<4)];
      s += wv.x*hv.x + wv.y*hv.y + wv.z*hv.z + wv.w*hv.w;
    }
    s += __shfl_xor(s, 1);
    s += __shfl_xor(s, 2);
    s += __shfl_xor(s, 4);
    s += __shfl_xor(s, 8);
    if (l16 == 0) phis[m] = s + b_g[m];
  }
  __syncthreads();
  if (tid == 0) {
    float mx = -1e30f;
    #pragma unroll
    for (int m = 0; m < Mz; m++) mx = fmaxf(mx, phis[2*Mz + m]);
    float ae[Mz], ssum = 0.f;
    #pragma unroll
    for (int m = 0; m < Mz; m++) { ae[m] = expf(phis[2*Mz + m] - mx); ssum += ae[m]; }
    float lo = 1e30f, hi = -1e30f;
    #pragma unroll
    for (int m = 0; m < Mz; m++) {
      float ks = expf(phis[m]);
      float be = expf(phis[Mz + m]);
      prm[m]        = ks;
      prm[Mz + m]   = expf(-phis[Mz + m]);
      prm[2*Mz + m] = ae[m] / ssum;
      lo = fminf(lo, ks - 0.5f - 25.f*be);
      hi = fmaxf(hi, ks + 0.5f + 25.f*be);
    }
    int llo = lo > 0.f ? (int)floorf(lo) : 0;
    if (llo > Lz) llo = Lz;
    int lhi = hi < (float)Lz ? (int)ceilf(hi) + 1 : Lz;
    if (lhi > Lz) lhi = Lz;
    rng[0] = llo; rng[1] = lhi;
  }
  __syncthreads();
  const int llo = rng[0], lhi = rng[1];
  for (int l = llo + tid; l < lhi; l += 512) {
    float u = (float)l;
    float t1 = 0.f, t0 = 0.f;
    #pragma unroll
    for (int m = 0; m < Mz; m++) {
      float ks = prm[m], ib = prm[Mz + m], al = prm[2*Mz + m];
      t1 += al * fsig((u + 0.5f - ks) * ib);
      t0 += al * fsig((u - 0.5f - ks) * ib);
    }
    float w = t1 - t0;
    wsm[l] = w;
    align_out[((size_t)b*Tz + (Tz-1))*Lz + l] = w;
  }
  __syncthreads();
  {
    const int grp = tid >> 7, d0 = (tid & 127) << 2;
    const float* mb = memory + (size_t)b*Lz*Dz + d0;
    float4 a = make_float4(0.f, 0.f, 0.f, 0.f);
    for (int l = llo + grp; l < lhi; l += 4) {
      float wl = wsm[l];
      float4 m0 = *reinterpret_cast<const float4*>(&mb[(size_t)l*Dz]);
      a.x = fmaf(wl, m0.x, a.x); a.y = fmaf(wl, m0.y, a.y);
      a.z = fmaf(wl, m0.z, a.z); a.w = fmaf(wl, m0.w, a.w);
    }
    *reinterpret_cast<float4*>(&pgemv[grp][d0]) = a;
  }
  __syncthreads();
  ctx_out[b*Dz + tid] = pgemv[0][tid] + pgemv[1][tid] + pgemv[2][tid] + pgemv[3][tid];
  if (tid == 0) {
    float u = (float)(lens[b] - 1);
    float t1 = 0.f;
    #pragma unroll
    for (int m = 0; m < Mz; m++)
      t1 += prm[2*Mz + m] * fsig((u + 0.5f - prm[m]) * prm[Mz + m]);
    term_out[b] = 1.0f - t1;
  }
}

// ================= fallback (small ws): two-kernel loop path =================
__global__ __launch_bounds__(256) void k_gemm(
    const float* __restrict__ x_all, const float* __restrict__ ctxs,
    const float* __restrict__ h, const float* __restrict__ W_ih,
    const float* __restrict__ W_hh, float* __restrict__ partial, int t)
{
  __shared__ float Xs[Bz][130];
  __shared__ float Wt[128][130];
  const int jt = blockIdx.x, kcb = blockIdx.y;
  const int j0 = jt*128, k0 = kcb*128;
  const int tid = threadIdx.x;
  for (int i = tid; i < Bz*128; i += 256) {
    int bb = i >> 7, kk = i & 127;
    int k = k0 + kk;
    float v;
    if (k < Dz)        v = x_all[((size_t)bb*Tz + t)*Dz + k];
    else if (k < 2*Dz) v = ctxs[bb*Dz + (k - Dz)];
    else               v = h[bb*Dz + (k - 2*Dz)];
    Xs[bb][kk] = v;
  }
  {
    const float* Wsrc; int ldw, col0;
    if (k0 < 2*Dz) { Wsrc = W_ih; ldw = 2*Dz; col0 = k0; }
    else           { Wsrc = W_hh; ldw = Dz;   col0 = k0 - 2*Dz; }
    for (int i = tid; i < 128*32; i += 256) {
      int jj = i >> 5, k4 = (i & 31) << 2;
      float4 v = *reinterpret_cast<const float4*>(&Wsrc[(size_t)(j0 + jj)*ldw + col0 + k4]);
      Wt[jj][k4] = v.x; Wt[jj][k4+1] = v.y; Wt[jj][k4+2] = v.z; Wt[jj][k4+3] = v.w;
    }
  }
  __syncthreads();
  const int jg = tid & 31, bg = tid >> 5;
  const int bl = bg << 2;
  float acc[4][4] = {};
  #pragma unroll 4
  for (int k = 0; k < 128; k += 2) {
    float2 xv[4], wv[4];
    #pragma unroll
    for (int b2 = 0; b2 < 4; b2++)
      xv[b2] = *reinterpret_cast<const float2*>(&Xs[bl + b2][k]);
    #pragma unroll
    for (int jj = 0; jj < 4; jj++)
      wv[jj] = *reinterpret_cast<const float2*>(&Wt[jg + (jj << 5)][k]);
    #pragma unroll
    for (int jj = 0; jj < 4; jj++)
      #pragma unroll
      for (int b2 = 0; b2 < 4; b2++)
        acc[jj][b2] += wv[jj].x * xv[b2].x + wv[jj].y * xv[b2].y;
  }
  #pragma unroll
  for (int jj = 0; jj < 4; jj++)
    #pragma unroll
    for (int b2 = 0; b2 < 4; b2++)
      partial[((size_t)kcb*Bz + (bl + b2))*G4D + j0 + jg + (jj << 5)] = acc[jj][b2];
}

__global__ __launch_bounds__(512) void k_fused(
    const float* __restrict__ partial, const float* __restrict__ b_ih,
    const float* __restrict__ b_hh,
    float* __restrict__ h, float* __restrict__ c,
    const float* __restrict__ W_g, const float* __restrict__ b_g,
    const float* __restrict__ memory, const int* __restrict__ lens,
    float* __restrict__ ctxs, float* __restrict__ ctx_out,
    float* __restrict__ align_out, float* __restrict__ term_out,
    int t, int final_, int nkc)
{
  const int b = blockIdx.x, tid = threadIdx.x;
  __shared__ float4 gs4[G4D/4];
  __shared__ float hsb[Dz];
  __shared__ float phis[3*Mz];
  __shared__ float prm[3*Mz];
  __shared__ float wsm[Lz];
  __shared__ int   rng[2];
  float* gs = (float*)gs4;
  {
    int j = 4*tid;
    float4 bi = *reinterpret_cast<const float4*>(&b_ih[j]);
    float4 bh = *reinterpret_cast<const float4*>(&b_hh[j]);
    float4 s = make_float4(bi.x+bh.x, bi.y+bh.y, bi.z+bh.z, bi.w+bh.w);
    const float4* pp = reinterpret_cast<const float4*>(partial) + (size_t)b*(G4D/4) + tid;
    for (int kcb = 0; kcb < nkc; kcb++) {
      float4 p = pp[(size_t)kcb*Bz*(G4D/4)];
      s.x += p.x; s.y += p.y; s.z += p.z; s.w += p.w;
    }
    gs4[tid] = s;
  }
  __syncthreads();
  {
    const int d = tid;
    float ig = 1.0f / (1.0f + expf(-gs[d]));
    float fg = 1.0f / (1.0f + expf(-gs[Dz + d]));
    float gg = tanhf(gs[2*Dz + d]);
    float og = 1.0f / (1.0f + expf(-gs[3*Dz + d]));
    float cn = fg * c[b*Dz + d] + ig * gg;
    float hn = og * tanhf(cn);
    c[b*Dz + d] = cn;
    h[b*Dz + d] = hn;
    hsb[d] = hn;
  }
  __syncthreads();
  if (tid < 16*3*Mz) {
    int m = tid >> 4, l16 = tid & 15;
    float s = 0.f;
    #pragma unroll 4
    for (int k = l16; k < Dz; k += 16) s += W_g[m*Dz + k] * hsb[k];
    s += __shfl_xor(s, 1);
    s += __shfl_xor(s, 2);
    s += __shfl_xor(s, 4);
    s += __shfl_xor(s, 8);
    if (l16 == 0) phis[m] = s + b_g[m];
  }
  __syncthreads();
  if (tid == 0) {
    float mx = -1e30f;
    #pragma unroll
    for (int m = 0; m < Mz; m++) mx = fmaxf(mx, phis[2*Mz + m]);
    float ae[Mz], ssum = 0.f;
    #pragma unroll
    for (int m = 0; m < Mz; m++) { ae[m] = expf(phis[2*Mz + m] - mx); ssum += ae[m]; }
    float lo = 1e30f, hi = -1e30f;
    #pragma unroll
    for (int m = 0; m < Mz; m++) {
      float ks = expf(phis[m]);
      float be = expf(phis[Mz + m]);
      prm[m]        = ks;
      prm[Mz + m]   = expf(-phis[Mz + m]);
      prm[2*Mz + m] = ae[m] / ssum;
      lo = fminf(lo, ks - 0.5f - 25.f*be);
      hi = fmaxf(hi, ks + 0.5f + 25.f*be);
    }
    int llo = lo > 0.f ? (int)floorf(lo) : 0;
    if (llo > Lz) llo = Lz;
    int lhi = hi < (float)Lz ? (int)ceilf(hi) + 1 : Lz;
    if (lhi > Lz) lhi = Lz;
    rng[0] = llo; rng[1] = lhi;
  }
  __syncthreads();
  const int llo = rng[0], lhi = rng[1];
  for (int l = llo + tid; l < lhi; l += 512) {
    float u = (float)l;
    float t1 = 0.f, t0 = 0.f;
    #pragma unroll
    for (int m = 0; m < Mz; m++) {
      float ks = prm[m], ib = prm[Mz + m], al = prm[2*Mz + m];
      t1 += al * fsig((u + 0.5f - ks) * ib);
      t0 += al * fsig((u - 0.5f - ks) * ib);
    }
    float w = t1 - t0;
    wsm[l] = w;
    align_out[((size_t)b*Tz + t)*Lz + l] = w;
  }
  __syncthreads();
  {
    const float* mb = memory + (size_t)b*Lz*Dz + tid;
    float acc = 0.f;
    #pragma unroll 4
    for (int l = llo; l < lhi; l++)
      acc += wsm[l] * mb[(size_t)l*Dz];
    ctxs[b*Dz + tid] = acc;
    if (final_) ctx_out[b*Dz + tid] = acc;
  }
  if (final_ && tid == 0) {
    float u = (float)(lens[b] - 1);
    float t1 = 0.f;
    #pragma unroll
    for (int m = 0; m < Mz; m++)
      t1 += prm[2*Mz + m] * fsig((u + 0.5f - prm[m]) * prm[Mz + m]);
    term_out[b] = 1.0f - t1;
  }
}

extern "C" void kernel_launch(void* const* d_in, const int* in_sizes, int n_in,
                              void* d_out, int out_size, void* d_ws, size_t ws_size,
                              hipStream_t stream)
{
  (void)in_sizes; (void)n_in; (void)out_size;
  const float* x    = (const float*)d_in[0];
  const float* mem  = (const float*)d_in[1];
  const int*   lens = (const int*)d_in[2];
  const float* W_ih = (const float*)d_in[3];
  const float* W_hh = (const float*)d_in[4];
  const float* b_ih = (const float*)d_in[5];
  const float* b_hh = (const float*)d_in[6];
  const float* W_g  = (const float*)d_in[7];
  const float* b_g  = (const float*)d_in[8];

  float* out = (float*)d_out;
  float* ctx_out   = out;                                  // [B,1,D]
  float* align_out = out + Bz*Dz;                          // [B,T,L]
  float* term_out  = out + Bz*Dz + (size_t)Bz*Tz*Lz;       // [B,1]

  const size_t needP = (size_t)NEED_I * sizeof(int);

  hipMemsetAsync(align_out, 0, (size_t)Bz*Tz*Lz*sizeof(float), stream);

  if (ws_size >= needP) {
    int*   ip  = (int*)d_ws;
    int*   fQ  = ip + OFF_FQ;
    float* hx  = (float*)(ip + OFF_HX);
    u32*   Wq  = (u32*)(ip + OFF_WQ);
    u32*   M2u = (u32*)(ip + OFF_M2);
    u32*   xwu = (u32*)(ip + OFF_XW);

    hipMemsetAsync(d_ws, 0, (size_t)OFF_HX * sizeof(int), stream);  // flags only
    k_pre<<<dim3((Bz*Tz)/PM, G4D/PN), 256, 0, stream>>>(x, W_ih, b_ih, b_hh, xwu);
    k_m2<<<dim3(16, 16), 512, 0, stream>>>(mem, W_ih, M2u);
    k_packh<<<256, 512, 0, stream>>>(W_hh, Wq);
    k_persist<<<NBLK, 512, 0, stream>>>(mem, lens, W_g, b_g, xwu, M2u, Wq,
                                        hx, fQ, ctx_out, align_out, term_out);
  } else {
    float* wsf     = (float*)d_ws;
    float* h       = wsf;
    float* c       = h + Bz*Dz;
    float* ctxs    = c + Bz*Dz;
    float* partial = ctxs + Bz*Dz;               // [12][B][4D]
    hipMemsetAsync(d_ws, 0, (size_t)(3*Bz*Dz)*sizeof(float), stream);
    for (int t = 0; t < Tz; t++) {
      k_gemm<<<dim3(G4D/128, 12), 256, 0, stream>>>(x, ctxs, h, W_ih, W_hh, partial, t);
      k_fused<<<Bz, 512, 0, stream>>>(partial, b_ih, b_hh, h, c, W_g, b_g,
                                      mem, lens, ctxs, ctx_out, align_out, term_out,
                                      t, t == Tz-1, 12);
    }
  }
}

// Round 18
// 5626.111 us; speedup vs baseline: 1.1943x; 1.0264x over previous
//
#include <hip/hip_runtime.h>

#define Bz 32
#define Tz 512
#define Dz 512
#define Lz 1024
#define Mz 10
#define G4D 2048
#define FP 32
#define NBQ 8                 // blocks per batch
#define NBLK (Bz*NBQ)         // 256
// ws int-region offsets
#define OFF_FQ   0                        // fQ[32][8][FP] = 8192
#define OFF_HXP  8192                     // hxp[2][32][256] u32 = 16384
#define OFF_WQ   24576                    // Wq[8][256][256] u32 = 524288 (2MB)
#define OFF_M2   548864                   // M2[32768][1024] u32 = 128MB
#define OFF_XW   34103296                 // xw[16384][1024] u32 = 64MB
#define NEED_I   50880512
// k_pre tiles
#define PM 128
#define PN 128
#define PK 32

typedef unsigned long long u64;
typedef unsigned u32;
typedef _Float16 f16x8 __attribute__((ext_vector_type(8)));
typedef float f32x4 __attribute__((ext_vector_type(4)));
typedef _Float16 half2_t __attribute__((ext_vector_type(2)));

#if defined(__has_builtin)
#if __has_builtin(__builtin_amdgcn_fdot2)
#define HAS_FDOT2 1
#endif
#endif

__device__ __forceinline__ float fsig(float x) { return 1.0f / (1.0f + __expf(-x)); }
__device__ __forceinline__ int ld_rlx(const int* p) {
  return __hip_atomic_load(p, __ATOMIC_RELAXED, __HIP_MEMORY_SCOPE_AGENT);
}
__device__ __forceinline__ void st_rlx(int* p, int v) {
  __hip_atomic_store(p, v, __ATOMIC_RELAXED, __HIP_MEMORY_SCOPE_AGENT);
}
__device__ __forceinline__ u32 ld_rlxu(const u32* p) {
  return __hip_atomic_load(p, __ATOMIC_RELAXED, __HIP_MEMORY_SCOPE_AGENT);
}
__device__ __forceinline__ void st_rlxu(u32* p, u32 v) {
  __hip_atomic_store(p, v, __ATOMIC_RELAXED, __HIP_MEMORY_SCOPE_AGENT);
}
__device__ __forceinline__ u32 pack16(float a, float b) {
  unsigned short la = __builtin_bit_cast(unsigned short, (_Float16)a);
  unsigned short lb = __builtin_bit_cast(unsigned short, (_Float16)b);
  return (u32)la | ((u32)lb << 16);
}
__device__ __forceinline__ float lo16(u32 v) {
  return (float)__builtin_bit_cast(half2_t, v)[0];
}
__device__ __forceinline__ float hi16(u32 v) {
  return (float)__builtin_bit_cast(half2_t, v)[1];
}
__device__ __forceinline__ float dot2f(u32 xu, u32 wu, float acc) {
  half2_t xh = __builtin_bit_cast(half2_t, xu);
  half2_t wh = __builtin_bit_cast(half2_t, wu);
#ifdef HAS_FDOT2
  return __builtin_amdgcn_fdot2(xh, wh, acc, false);
#else
  return acc + (float)xh[0]*(float)wh[0] + (float)xh[1]*(float)wh[1];
#endif
}
#define VWAIT() asm volatile("s_waitcnt vmcnt(0)" ::: "memory")

// ---------------- K0 (once): xw_f16[bt][j] = x[bt,:].W_ih[j,0:512] + b_ih[j] + b_hh[j] ----------------
__global__ __launch_bounds__(256) void k_pre(
    const float* __restrict__ x, const float* __restrict__ W_ih,
    const float* __restrict__ b_ih, const float* __restrict__ b_hh,
    u32* __restrict__ xwu)
{
  __shared__ float As[PM][PK+1];
  __shared__ float Bs[PN][PK+1];
  const int m0 = blockIdx.x*PM, n0 = blockIdx.y*PN;
  const int tid = threadIdx.x;
  const int mg = tid >> 4, ng = tid & 15;
  float acc[8][8] = {};
  for (int k0 = 0; k0 < Dz; k0 += PK) {
    for (int i = tid; i < PM*(PK/4); i += 256) {
      int row = i >> 3, c4 = (i & 7) << 2;
      float4 v = *reinterpret_cast<const float4*>(&x[(size_t)(m0+row)*Dz + k0 + c4]);
      As[row][c4] = v.x; As[row][c4+1] = v.y; As[row][c4+2] = v.z; As[row][c4+3] = v.w;
    }
    for (int i = tid; i < PN*(PK/4); i += 256) {
      int row = i >> 3, c4 = (i & 7) << 2;
      float4 v = *reinterpret_cast<const float4*>(&W_ih[(size_t)(n0+row)*(2*Dz) + k0 + c4]);
      Bs[row][c4] = v.x; Bs[row][c4+1] = v.y; Bs[row][c4+2] = v.z; Bs[row][c4+3] = v.w;
    }
    __syncthreads();
    #pragma unroll 8
    for (int k = 0; k < PK; k++) {
      float a8[8], b8[8];
      #pragma unroll
      for (int r = 0; r < 8; r++) a8[r] = As[mg*8+r][k];
      #pragma unroll
      for (int s = 0; s < 8; s++) b8[s] = Bs[ng*8+s][k];
      #pragma unroll
      for (int r = 0; r < 8; r++)
        #pragma unroll
        for (int s = 0; s < 8; s++) acc[r][s] += a8[r]*b8[s];
    }
    __syncthreads();
  }
  const int nb = n0 + ng*8;
  #pragma unroll
  for (int r = 0; r < 8; r++) {
    int m = m0 + mg*8 + r;
    #pragma unroll
    for (int s2 = 0; s2 < 4; s2++) {
      int n = nb + 2*s2;
      xwu[(size_t)m*1024 + (n >> 1)] =
          pack16(acc[r][2*s2]   + b_ih[n]   + b_hh[n],
                 acc[r][2*s2+1] + b_ih[n+1] + b_hh[n+1]);
    }
  }
}

// ---------------- K1 (once): M2[m][j] = memory[m,:] . W_ic[j,:]  (f16 pairs, MFMA) ----------------
__global__ __launch_bounds__(512) void k_m2(
    const float* __restrict__ memory, const float* __restrict__ W_ih,
    u32* __restrict__ M2u)
{
  __shared__ __align__(16) u32 smem[149760/4];
  u32* Bs = smem;              // [128][260]
  u32* As = smem + 33280;      // [16][260]
  const int tid = threadIdx.x;
  const int n0 = blockIdx.x * 128, mc = blockIdx.y;
  for (int i = tid; i < 128*256; i += 512) {
    int jl = i >> 8, ku = i & 255;
    float2 wv = *reinterpret_cast<const float2*>(&W_ih[(size_t)(n0+jl)*(2*Dz) + 512 + 2*ku]);
    Bs[jl*260 + (ku ^ ((jl & 7) << 2))] = pack16(wv.x, wv.y);
  }
  __syncthreads();
  const int w = tid >> 6, lane = tid & 63;
  const int fr = lane & 15, kq = (lane >> 4) << 2;
  const int frsw = (fr & 7) << 2;
  for (int mt = 0; mt < 128; ++mt) {
    const int m0 = mc*2048 + mt*16;
    for (int i = tid; i < 16*256; i += 512) {
      int r = i >> 8, ku = i & 255;
      float2 mv = *reinterpret_cast<const float2*>(&memory[(size_t)(m0+r)*Dz + 2*ku]);
      As[r*260 + (ku ^ ((r & 7) << 2))] = pack16(mv.x, mv.y);
    }
    __syncthreads();
    f32x4 acc = {0.f, 0.f, 0.f, 0.f};
    #pragma unroll
    for (int ks = 0; ks < 16; ++ks) {
      int col = (kq + ks*16) ^ frsw;
      f16x8 av = *reinterpret_cast<const f16x8*>(As + fr*260 + col);
      f16x8 bv = *reinterpret_cast<const f16x8*>(Bs + (w*16 + fr)*260 + col);
      acc = __builtin_amdgcn_mfma_f32_16x16x32_f16(av, bv, acc, 0, 0, 0);
    }
    #pragma unroll
    for (int i = 0; i < 4; ++i) {
      float oth = __shfl_xor(acc[i], 1);
      if (!(lane & 1)) {
        int m = m0 + ((lane >> 4) << 2) + i;
        int j = n0 + w*16 + fr;
        M2u[(size_t)m*1024 + (j >> 1)] = pack16(acc[i], oth);
      }
    }
    __syncthreads();
  }
}

// ---------------- K2 (once): Wq[q][kp][pos] = pack(Whh[j][2kp], Whh[j][2kp+1]) ----------------
// pos = g*64 + jj ; j = 512*g + 64*q + jj
__global__ __launch_bounds__(512) void k_packh(
    const float* __restrict__ W_hh, u32* __restrict__ Wq)
{
  const int kp = blockIdx.x;
  for (int idx = threadIdx.x; idx < 2048; idx += 512) {
    int q = idx >> 8, pos = idx & 255;
    int g = pos >> 6, jj = pos & 63;
    int j = 512*g + 64*q + jj;
    float2 wv = *reinterpret_cast<const float2*>(&W_hh[(size_t)j*Dz + 2*kp]);
    Wq[(size_t)q*65536 + kp*256 + pos] = pack16(wv.x, wv.y);
  }
}

// ---- intra-tail-half sync: monotonic LDS counters, 4 tail-wave leaders each ----
#define HSYNC(id, tgt) do {                                                    \
  __threadfence_block();                                                       \
  if ((tid & 63) == 0) atomicAdd(&scnt[id], 1);                                \
  while (__hip_atomic_load(&scnt[id], __ATOMIC_RELAXED,                        \
                           __HIP_MEMORY_SCOPE_WORKGROUP) < (tgt))              \
    __builtin_amdgcn_s_sleep(1);                                               \
  __threadfence_block();                                                       \
} while (0)

// ---------------- Persistent kernel: wave-specialized GEMV || TAIL, packed-f16 exchange ----------------
__global__ __launch_bounds__(512) void k_persist(
    const float* __restrict__ memory, const int* __restrict__ lens,
    const float* __restrict__ W_g,  const float* __restrict__ b_g,
    const u32* __restrict__ xwu, const u32* __restrict__ M2u,
    const u32* __restrict__ Wq,
    u32* __restrict__ hxp, int* __restrict__ fQ,
    float* __restrict__ ctx_out, float* __restrict__ align_out,
    float* __restrict__ term_out)
{
  const int blk = blockIdx.x, tid = threadIdx.x;
  const int b = blk >> 3, q = blk & 7;

  __shared__ float pgemv[4][512];     // GEMV uses [4][256]; post-loop einsum [4][512]
  __shared__ float gctxl[256];        // ctx gate contribution for own 256 gate rows
  __shared__ float wsm[Lz];
  __shared__ float cs[64];
  __shared__ u32   xp[256];           // h(t-1) packed f16 pairs (shared by GEMV+tail)
  __shared__ u32   wgp[3*Mz*256];     // W_g packed f16 (30 KB, staged once)
  __shared__ float phis[3*Mz], prm[3*Mz];
  __shared__ int   rng[2];
  __shared__ int   scnt[3];

  if (tid < 64)  cs[tid] = 0.f;
  if (tid < 256) { xp[tid] = 0u; gctxl[tid] = 0.f; }   // h(-1)=ctx(-1)=0
  if (tid < 3)   scnt[tid] = 0;
  for (int i = tid; i < 3*Mz*256; i += 512) {
    int m = i >> 8, ku = i & 255;
    float2 wv = *reinterpret_cast<const float2*>(&W_g[(size_t)m*Dz + 2*ku]);
    wgp[i] = pack16(wv.x, wv.y);
  }
  __syncthreads();

  const uint4* wq4 = reinterpret_cast<const uint4*>(Wq) + (size_t)q*16384;

  for (int t = 0; t < Tz; ++t) {
    // prefetch xw gate biases for LSTM(t) (hidden under GEMV)
    u32 xwp0 = 0, xwp1 = 0, xwp2 = 0, xwp3 = 0;
    if (tid < 64) {
      const size_t xwb = ((size_t)(b*Tz + t)) << 10;
      const int o = (q << 5) + (tid >> 1);
      xwp0 = xwu[xwb + o];
      xwp1 = xwu[xwb + 256 + o];
      xwp2 = xwu[xwb + 512 + o];
      xwp3 = xwu[xwb + 768 + o];
    }

    if (tid < 256) {
      // ======== GEMV half (waves 0-3): own 256 gate rows, K=512, from xp=h(t-1)
      const int kg2 = tid >> 6, tq2 = tid & 63;
      const uint4* wr = wq4 + tq2;
      float a0 = 0.f, a1 = 0.f, a2 = 0.f, a3 = 0.f;
      const int k0 = kg2 << 6;
      #pragma unroll 4
      for (int kp = k0; kp < k0 + 64; ++kp) {
        uint4 wv = wr[(size_t)kp << 6];
        u32 xv = xp[kp];
        a0 = dot2f(xv, wv.x, a0);
        a1 = dot2f(xv, wv.y, a1);
        a2 = dot2f(xv, wv.z, a2);
        a3 = dot2f(xv, wv.w, a3);
      }
      *reinterpret_cast<float4*>(&pgemv[kg2][tq2 << 2]) = make_float4(a0, a1, a2, a3);
    } else if (t > 0) {
      // ======== TAIL half (waves 4-7): derived from h(t-1) (packed in xp)
      const int t2 = tid - 256;
      const int tgt = 4 * t;
      if (t2 < 8*3*Mz) {
        int m = t2 >> 3, l8 = t2 & 7;
        const u32* wr2 = wgp + (m << 8);
        float s = 0.f;
        #pragma unroll
        for (int i = 0; i < 32; i++) {
          int ku = l8 + (i << 3);
          s = dot2f(xp[ku], wr2[ku], s);
        }
        s += __shfl_xor(s, 1);
        s += __shfl_xor(s, 2);
        s += __shfl_xor(s, 4);
        if (l8 == 0) phis[m] = s + b_g[m];
      }
      HSYNC(0, tgt);
      if (t2 == 0) {
        float mx = -1e30f;
        #pragma unroll
        for (int m = 0; m < Mz; m++) mx = fmaxf(mx, phis[2*Mz + m]);
        float ae[Mz], ssum = 0.f;
        #pragma unroll
        for (int m = 0; m < Mz; m++) { ae[m] = expf(phis[2*Mz + m] - mx); ssum += ae[m]; }
        float lo = 1e30f, hi = -1e30f;
        #pragma unroll
        for (int m = 0; m < Mz; m++) {
          float ks = expf(phis[m]);
          float be = expf(phis[Mz + m]);
          prm[m]        = ks;
          prm[Mz + m]   = expf(-phis[Mz + m]);   // 1/beta
          prm[2*Mz + m] = ae[m] / ssum;
          lo = fminf(lo, ks - 0.5f - 25.f*be);   // sig(-25) < fp32 visibility
          hi = fmaxf(hi, ks + 0.5f + 25.f*be);
        }
        int llo = lo > 0.f ? (int)floorf(lo) : 0;
        if (llo > Lz) llo = Lz;
        int lhi = hi < (float)Lz ? (int)ceilf(hi) + 1 : Lz;
        if (lhi > Lz) lhi = Lz;
        rng[0] = llo; rng[1] = lhi;
      }
      HSYNC(1, tgt);
      const int llo = rng[0], lhi = rng[1];
      for (int l = llo + t2; l < lhi; l += 256) {
        float u = (float)l;
        float t1 = 0.f, t0 = 0.f;
        #pragma unroll
        for (int m = 0; m < Mz; m++) {
          float ks = prm[m], ib = prm[Mz + m], al = prm[2*Mz + m];
          t1 += al * fsig((u + 0.5f - ks) * ib);
          t0 += al * fsig((u - 0.5f - ks) * ib);
        }
        wsm[l] = t1 - t0;
      }
      HSYNC(2, tgt);
      // gctx(t) for own 256 gate rows: 128 u32 cols, 1 per thread (t2<128)
      if (t2 < 128) {
        const int g = t2 >> 5, jc2 = t2 & 31;
        const int col = (g << 8) + (q << 5) + jc2;
        const u32* m2c = M2u + (((size_t)b << 10) << 10) + col;
        float alo0 = 0.f, ahi0 = 0.f, alo1 = 0.f, ahi1 = 0.f;
        int l = llo;
        for (; l + 1 < lhi; l += 2) {
          float w0 = wsm[l], w1 = wsm[l+1];
          u32 v0 = m2c[(size_t)l << 10];
          u32 v1 = m2c[(size_t)(l+1) << 10];
          alo0 = fmaf(w0, lo16(v0), alo0); ahi0 = fmaf(w0, hi16(v0), ahi0);
          alo1 = fmaf(w1, lo16(v1), alo1); ahi1 = fmaf(w1, hi16(v1), ahi1);
        }
        if (l < lhi) {
          float w0 = wsm[l]; u32 v0 = m2c[(size_t)l << 10];
          alo0 = fmaf(w0, lo16(v0), alo0); ahi0 = fmaf(w0, hi16(v0), ahi0);
        }
        gctxl[(g << 6) + 2*jc2]     = alo0 + alo1;
        gctxl[(g << 6) + 2*jc2 + 1] = ahi0 + ahi1;
      }
      // align(t-1) (q==0 only; overlapped with GEMV)
      if (q == 0) {
        for (int l = llo + t2; l < lhi; l += 256)
          align_out[((size_t)b*Tz + (t-1))*Lz + l] = wsm[l];
      }
    }
    __syncthreads();   // join

    // ======== LSTM(t): d in [64q, 64q+64), gate order i,f,g,o; publish packed
    if (tid < 64) {
      const int dl = tid;
      u32 xwp[4] = {xwp0, xwp1, xwp2, xwp3};
      float gv[4];
      #pragma unroll
      for (int g = 0; g < 4; ++g) {
        int pos = (g << 6) + dl;
        float s = pgemv[0][pos] + pgemv[1][pos] + pgemv[2][pos] + pgemv[3][pos]
                + gctxl[pos];
        s += (dl & 1) ? hi16(xwp[g]) : lo16(xwp[g]);
        gv[g] = s;
      }
      float ig = fsig(gv[0]);
      float fg = fsig(gv[1]);
      float gg = tanhf(gv[2]);
      float og = fsig(gv[3]);
      float cn = fg*cs[dl] + ig*gg;
      float hn = og*tanhf(cn);
      cs[dl] = cn;
      float hnb = __shfl_down(hn, 1);
      if (!(dl & 1))
        st_rlxu(&hxp[((t & 1)*Bz + b)*256 + (q << 5) + (dl >> 1)], pack16(hn, hnb));
    }
    VWAIT();
    __syncthreads();
    if (tid == 0) st_rlx(&fQ[(b*NBQ + q)*FP], t+1);

    // poll siblings, gather packed h directly into xp (no repack step)
    if (tid < NBQ) {
      while (ld_rlx(&fQ[(b*NBQ + tid)*FP]) < t+1) __builtin_amdgcn_s_sleep(1);
    }
    __syncthreads();
    if (tid < 256) xp[tid] = ld_rlxu(&hxp[((t & 1)*Bz + b)*256 + tid]);
    __syncthreads();
  }

  // ======== post-loop: TAIL(T-1) + outputs, q==0 only, full block ========
  if (q != 0) return;
  if (tid < 8*3*Mz) {
    int m = tid >> 3, l8 = tid & 7;
    const u32* wr2 = wgp + (m << 8);
    float s = 0.f;
    #pragma unroll
    for (int i = 0; i < 32; i++) {
      int ku = l8 + (i << 3);
      s = dot2f(xp[ku], wr2[ku], s);
    }
    s += __shfl_xor(s, 1);
    s += __shfl_xor(s, 2);
    s += __shfl_xor(s, 4);
    if (l8 == 0) phis[m] = s + b_g[m];
  }
  __syncthreads();
  if (tid == 0) {
    float mx = -1e30f;
    #pragma unroll
    for (int m = 0; m < Mz; m++) mx = fmaxf(mx, phis[2*Mz + m]);
    float ae[Mz], ssum = 0.f;
    #pragma unroll
    for (int m = 0; m < Mz; m++) { ae[m] = expf(phis[2*Mz + m] - mx); ssum += ae[m]; }
    float lo = 1e30f, hi = -1e30f;
    #pragma unroll
    for (int m = 0; m < Mz; m++) {
      float ks = expf(phis[m]);
      float be = expf(phis[Mz + m]);
      prm[m]        = ks;
      prm[Mz + m]   = expf(-phis[Mz + m]);
      prm[2*Mz + m] = ae[m] / ssum;
      lo = fminf(lo, ks - 0.5f - 25.f*be);
      hi = fmaxf(hi, ks + 0.5f + 25.f*be);
    }
    int llo = lo > 0.f ? (int)floorf(lo) : 0;
    if (llo > Lz) llo = Lz;
    int lhi = hi < (float)Lz ? (int)ceilf(hi) + 1 : Lz;
    if (lhi > Lz) lhi = Lz;
    rng[0] = llo; rng[1] = lhi;
  }
  __syncthreads();
  const int llo = rng[0], lhi = rng[1];
  for (int l = llo + tid; l < lhi; l += 512) {
    float u = (float)l;
    float t1 = 0.f, t0 = 0.f;
    #pragma unroll
    for (int m = 0; m < Mz; m++) {
      float ks = prm[m], ib = prm[Mz + m], al = prm[2*Mz + m];
      t1 += al * fsig((u + 0.5f - ks) * ib);
      t0 += al * fsig((u - 0.5f - ks) * ib);
    }
    float w = t1 - t0;
    wsm[l] = w;
    align_out[((size_t)b*Tz + (Tz-1))*Lz + l] = w;
  }
  __syncthreads();
  {
    const int grp = tid >> 7, d0 = (tid & 127) << 2;
    const float* mb = memory + (size_t)b*Lz*Dz + d0;
    float4 a = make_float4(0.f, 0.f, 0.f, 0.f);
    for (int l = llo + grp; l < lhi; l += 4) {
      float wl = wsm[l];
      float4 m0 = *reinterpret_cast<const float4*>(&mb[(size_t)l*Dz]);
      a.x = fmaf(wl, m0.x, a.x); a.y = fmaf(wl, m0.y, a.y);
      a.z = fmaf(wl, m0.z, a.z); a.w = fmaf(wl, m0.w, a.w);
    }
    *reinterpret_cast<float4*>(&pgemv[grp][d0]) = a;
  }
  __syncthreads();
  ctx_out[b*Dz + tid] = pgemv[0][tid] + pgemv[1][tid] + pgemv[2][tid] + pgemv[3][tid];
  if (tid == 0) {
    float u = (float)(lens[b] - 1);
    float t1 = 0.f;
    #pragma unroll
    for (int m = 0; m < Mz; m++)
      t1 += prm[2*Mz + m] * fsig((u + 0.5f - prm[m]) * prm[Mz + m]);
    term_out[b] = 1.0f - t1;
  }
}

// ================= fallback (small ws): two-kernel loop path =================
__global__ __launch_bounds__(256) void k_gemm(
    const float* __restrict__ x_all, const float* __restrict__ ctxs,
    const float* __restrict__ h, const float* __restrict__ W_ih,
    const float* __restrict__ W_hh, float* __restrict__ partial, int t)
{
  __shared__ float Xs[Bz][130];
  __shared__ float Wt[128][130];
  const int jt = blockIdx.x, kcb = blockIdx.y;
  const int j0 = jt*128, k0 = kcb*128;
  const int tid = threadIdx.x;
  for (int i = tid; i < Bz*128; i += 256) {
    int bb = i >> 7, kk = i & 127;
    int k = k0 + kk;
    float v;
    if (k < Dz)        v = x_all[((size_t)bb*Tz + t)*Dz + k];
    else if (k < 2*Dz) v = ctxs[bb*Dz + (k - Dz)];
    else               v = h[bb*Dz + (k - 2*Dz)];
    Xs[bb][kk] = v;
  }
  {
    const float* Wsrc; int ldw, col0;
    if (k0 < 2*Dz) { Wsrc = W_ih; ldw = 2*Dz; col0 = k0; }
    else           { Wsrc = W_hh; ldw = Dz;   col0 = k0 - 2*Dz; }
    for (int i = tid; i < 128*32; i += 256) {
      int jj = i >> 5, k4 = (i & 31) << 2;
      float4 v = *reinterpret_cast<const float4*>(&Wsrc[(size_t)(j0 + jj)*ldw + col0 + k4]);
      Wt[jj][k4] = v.x; Wt[jj][k4+1] = v.y; Wt[jj][k4+2] = v.z; Wt[jj][k4+3] = v.w;
    }
  }
  __syncthreads();
  const int jg = tid & 31, bg = tid >> 5;
  const int bl = bg << 2;
  float acc[4][4] = {};
  #pragma unroll 4
  for (int k = 0; k < 128; k += 2) {
    float2 xv[4], wv[4];
    #pragma unroll
    for (int b2 = 0; b2 < 4; b2++)
      xv[b2] = *reinterpret_cast<const float2*>(&Xs[bl + b2][k]);
    #pragma unroll
    for (int jj = 0; jj < 4; jj++)
      wv[jj] = *reinterpret_cast<const float2*>(&Wt[jg + (jj << 5)][k]);
    #pragma unroll
    for (int jj = 0; jj < 4; jj++)
      #pragma unroll
      for (int b2 = 0; b2 < 4; b2++)
        acc[jj][b2] += wv[jj].x * xv[b2].x + wv[jj].y * xv[b2].y;
  }
  #pragma unroll
  for (int jj = 0; jj < 4; jj++)
    #pragma unroll
    for (int b2 = 0; b2 < 4; b2++)
      partial[((size_t)kcb*Bz + (bl + b2))*G4D + j0 + jg + (jj << 5)] = acc[jj][b2];
}

__global__ __launch_bounds__(512) void k_fused(
    const float* __restrict__ partial, const float* __restrict__ b_ih,
    const float* __restrict__ b_hh,
    float* __restrict__ h, float* __restrict__ c,
    const float* __restrict__ W_g, const float* __restrict__ b_g,
    const float* __restrict__ memory, const int* __restrict__ lens,
    float* __restrict__ ctxs, float* __restrict__ ctx_out,
    float* __restrict__ align_out, float* __restrict__ term_out,
    int t, int final_, int nkc)
{
  const int b = blockIdx.x, tid = threadIdx.x;
  __shared__ float4 gs4[G4D/4];
  __shared__ float hsb[Dz];
  __shared__ float phis[3*Mz];
  __shared__ float prm[3*Mz];
  __shared__ float wsm[Lz];
  __shared__ int   rng[2];
  float* gs = (float*)gs4;
  {
    int j = 4*tid;
    float4 bi = *reinterpret_cast<const float4*>(&b_ih[j]);
    float4 bh = *reinterpret_cast<const float4*>(&b_hh[j]);
    float4 s = make_float4(bi.x+bh.x, bi.y+bh.y, bi.z+bh.z, bi.w+bh.w);
    const float4* pp = reinterpret_cast<const float4*>(partial) + (size_t)b*(G4D/4) + tid;
    for (int kcb = 0; kcb < nkc; kcb++) {
      float4 p = pp[(size_t)kcb*Bz*(G4D/4)];
      s.x += p.x; s.y += p.y; s.z += p.z; s.w += p.w;
    }
    gs4[tid] = s;
  }
  __syncthreads();
  {
    const int d = tid;
    float ig = 1.0f / (1.0f + expf(-gs[d]));
    float fg = 1.0f / (1.0f + expf(-gs[Dz + d]));
    float gg = tanhf(gs[2*Dz + d]);
    float og = 1.0f / (1.0f + expf(-gs[3*Dz + d]));
    float cn = fg * c[b*Dz + d] + ig * gg;
    float hn = og * tanhf(cn);
    c[b*Dz + d] = cn;
    h[b*Dz + d] = hn;
    hsb[d] = hn;
  }
  __syncthreads();
  if (tid < 16*3*Mz) {
    int m = tid >> 4, l16 = tid & 15;
    float s = 0.f;
    #pragma unroll 4
    for (int k = l16; k < Dz; k += 16) s += W_g[m*Dz + k] * hsb[k];
    s += __shfl_xor(s, 1);
    s += __shfl_xor(s, 2);
    s += __shfl_xor(s, 4);
    s += __shfl_xor(s, 8);
    if (l16 == 0) phis[m] = s + b_g[m];
  }
  __syncthreads();
  if (tid == 0) {
    float mx = -1e30f;
    #pragma unroll
    for (int m = 0; m < Mz; m++) mx = fmaxf(mx, phis[2*Mz + m]);
    float ae[Mz], ssum = 0.f;
    #pragma unroll
    for (int m = 0; m < Mz; m++) { ae[m] = expf(phis[2*Mz + m] - mx); ssum += ae[m]; }
    float lo = 1e30f, hi = -1e30f;
    #pragma unroll
    for (int m = 0; m < Mz; m++) {
      float ks = expf(phis[m]);
      float be = expf(phis[Mz + m]);
      prm[m]        = ks;
      prm[Mz + m]   = expf(-phis[Mz + m]);
      prm[2*Mz + m] = ae[m] / ssum;
      lo = fminf(lo, ks - 0.5f - 25.f*be);
      hi = fmaxf(hi, ks + 0.5f + 25.f*be);
    }
    int llo = lo > 0.f ? (int)floorf(lo) : 0;
    if (llo > Lz) llo = Lz;
    int lhi = hi < (float)Lz ? (int)ceilf(hi) + 1 : Lz;
    if (lhi > Lz) lhi = Lz;
    rng[0] = llo; rng[1] = lhi;
  }
  __syncthreads();
  const int llo = rng[0], lhi = rng[1];
  for (int l = llo + tid; l < lhi; l += 512) {
    float u = (float)l;
    float t1 = 0.f, t0 = 0.f;
    #pragma unroll
    for (int m = 0; m < Mz; m++) {
      float ks = prm[m], ib = prm[Mz + m], al = prm[2*Mz + m];
      t1 += al * fsig((u + 0.5f - ks) * ib);
      t0 += al * fsig((u - 0.5f - ks) * ib);
    }
    float w = t1 - t0;
    wsm[l] = w;
    align_out[((size_t)b*Tz + t)*Lz + l] = w;
  }
  __syncthreads();
  {
    const float* mb = memory + (size_t)b*Lz*Dz + tid;
    float acc = 0.f;
    #pragma unroll 4
    for (int l = llo; l < lhi; l++)
      acc += wsm[l] * mb[(size_t)l*Dz];
    ctxs[b*Dz + tid] = acc;
    if (final_) ctx_out[b*Dz + tid] = acc;
  }
  if (final_ && tid == 0) {
    float u = (float)(lens[b] - 1);
    float t1 = 0.f;
    #pragma unroll
    for (int m = 0; m < Mz; m++)
      t1 += prm[2*Mz + m] * fsig((u + 0.5f - prm[m]) * prm[Mz + m]);
    term_out[b] = 1.0f - t1;
  }
}

extern "C" void kernel_launch(void* const* d_in, const int* in_sizes, int n_in,
                              void* d_out, int out_size, void* d_ws, size_t ws_size,
                              hipStream_t stream)
{
  (void)in_sizes; (void)n_in; (void)out_size;
  const float* x    = (const float*)d_in[0];
  const float* mem  = (const float*)d_in[1];
  const int*   lens = (const int*)d_in[2];
  const float* W_ih = (const float*)d_in[3];
  const float* W_hh = (const float*)d_in[4];
  const float* b_ih = (const float*)d_in[5];
  const float* b_hh = (const float*)d_in[6];
  const float* W_g  = (const float*)d_in[7];
  const float* b_g  = (const float*)d_in[8];

  float* out = (float*)d_out;
  float* ctx_out   = out;                                  // [B,1,D]
  float* align_out = out + Bz*Dz;                          // [B,T,L]
  float* term_out  = out + Bz*Dz + (size_t)Bz*Tz*Lz;       // [B,1]

  const size_t needP = (size_t)NEED_I * sizeof(int);

  hipMemsetAsync(align_out, 0, (size_t)Bz*Tz*Lz*sizeof(float), stream);

  if (ws_size >= needP) {
    int*   ip  = (int*)d_ws;
    int*   fQ  = ip + OFF_FQ;
    u32*   hxp = (u32*)(ip + OFF_HXP);
    u32*   Wq  = (u32*)(ip + OFF_WQ);
    u32*   M2u = (u32*)(ip + OFF_M2);
    u32*   xwu = (u32*)(ip + OFF_XW);

    hipMemsetAsync(d_ws, 0, (size_t)OFF_WQ * sizeof(int), stream);  // flags + hxp
    k_pre<<<dim3((Bz*Tz)/PM, G4D/PN), 256, 0, stream>>>(x, W_ih, b_ih, b_hh, xwu);
    k_m2<<<dim3(16, 16), 512, 0, stream>>>(mem, W_ih, M2u);
    k_packh<<<256, 512, 0, stream>>>(W_hh, Wq);
    k_persist<<<NBLK, 512, 0, stream>>>(mem, lens, W_g, b_g, xwu, M2u, Wq,
                                        hxp, fQ, ctx_out, align_out, term_out);
  } else {
    float* wsf     = (float*)d_ws;
    float* h       = wsf;
    float* c       = h + Bz*Dz;
    float* ctxs    = c + Bz*Dz;
    float* partial = ctxs + Bz*Dz;               // [12][B][4D]
    hipMemsetAsync(d_ws, 0, (size_t)(3*Bz*Dz)*sizeof(float), stream);
    for (int t = 0; t < Tz; t++) {
      k_gemm<<<dim3(G4D/128, 12), 256, 0, stream>>>(x, ctxs, h, W_ih, W_hh, partial, t);
      k_fused<<<Bz, 512, 0, stream>>>(partial, b_ih, b_hh, h, c, W_g, b_g,
                                      mem, lens, ctxs, ctx_out, align_out, term_out,
                                      t, t == Tz-1, 12);
    }
  }
}